// Round 5
// baseline (989.750 us; speedup 1.0000x reference)
//
#include <hip/hip_runtime.h>
#include <math.h>

#define LN2F 0.6931471805599453f
#define ATG 8
#define CHUNK 128

typedef _Float16 half_t;
typedef _Float16 half4_t __attribute__((ext_vector_type(4)));
typedef float f32x4 __attribute__((ext_vector_type(4)));

__device__ __forceinline__ float sspf(float z) {
    // ssp(z) = max(z,0) + log(1+exp(-|z|)) - ln2   (fast HW intrinsics)
    return fmaxf(z, 0.f) + __logf(1.f + __expf(-fabsf(z))) - LN2F;
}
__device__ __forceinline__ half4_t cvt4(float x, float y, float z, float w) {
    half4_t r; r[0]=(half_t)x; r[1]=(half_t)y; r[2]=(half_t)z; r[3]=(half_t)w; return r;
}

// Weight prep:
//  Wt_in2f/Wt_o1/Wt_o2: dst[n*128+k] = W[k][n]          (f16, for mfma_gemm B)
//  Wt_f1:               dst[n*32+k]  = W_f1[k][n], k<20 else 0   (f16, phase-1 A)
//  W2L: custom lane-linear layout for edge phase-2 B frags:
//       W2L[(((kk*8+nt)*4+g)*16+ln)*4 + j] = W_f2[kk*16+g*4+j][nt*16+ln]
__global__ __launch_bounds__(256) void prep_weights(
    const float* __restrict__ W_in2f, const float* __restrict__ W_f1,
    const float* __restrict__ W_f2, const float* __restrict__ W_o1,
    const float* __restrict__ W_o2,
    half_t* __restrict__ Wt_in2f, half_t* __restrict__ Wt_f1,
    half_t* __restrict__ W2L, half_t* __restrict__ Wt_o1,
    half_t* __restrict__ Wt_o2)
{
    int b = blockIdx.x;
    if (b < 64) {
        int i = b*256 + threadIdx.x;            // n*128+k
        Wt_in2f[i] = (half_t)W_in2f[(i & 127)*128 + (i >> 7)];
    } else if (b < 80) {
        int i = (b-64)*256 + threadIdx.x;       // n*32+k
        int n = i >> 5, k = i & 31;
        Wt_f1[i] = (k < 20) ? (half_t)W_f1[k*128 + n] : (half_t)0.f;
    } else if (b < 144) {
        int hidx = (b-80)*256 + threadIdx.x;    // 0..16383
        int j = hidx & 3, i4 = hidx >> 2;
        int ln = i4 & 15, g = (i4 >> 4) & 3, nt = (i4 >> 6) & 7, kk = i4 >> 9;
        W2L[hidx] = (half_t)W_f2[(kk*16 + g*4 + j)*128 + nt*16 + ln];
    } else if (b < 208) {
        int i = (b-144)*256 + threadIdx.x;
        Wt_o1[i] = (half_t)W_o1[(i & 127)*128 + (i >> 7)];
    } else {
        int i = (b-208)*256 + threadIdx.x;
        Wt_o2[i] = (half_t)W_o2[(i & 127)*128 + (i >> 7)];
    }
}

// atom_start[a] = first edge index with idx_i >= a; atom_start[N] = E
__global__ __launch_bounds__(256) void seg_starts(
    const int* __restrict__ idx_i, int* __restrict__ atom_start, int E, int N)
{
    int e = blockIdx.x * 256 + threadIdx.x;
    if (e >= E) return;
    int a = idx_i[e];
    int prev = (e == 0) ? -1 : idx_i[e - 1];
    for (int k = prev + 1; k <= a; ++k) atom_start[k] = e;
    if (e == E - 1)
        for (int k = a + 1; k <= N; ++k) atom_start[k] = E;
}

// C = act(A @ B + bias); A:[nrows,128] f32, Bt f16 (Bt[n][k]=B[k][n])
// mode: 0 = f32 out, 1 = f32 out + ssp, 2 = f16 out (Ch)
__global__ __launch_bounds__(256) void mfma_gemm(
    const float* __restrict__ A, const half_t* __restrict__ Bt,
    const float* __restrict__ bias, float* __restrict__ C,
    half_t* __restrict__ Ch, int nrows, int mode)
{
    const int tid = threadIdx.x;
    const int w = tid >> 6, l = tid & 63, g = l >> 4, ln = l & 15;
    const int r0 = blockIdx.x * 64;

    f32x4 acc[4][2];
    #pragma unroll
    for (int rf = 0; rf < 4; ++rf)
        #pragma unroll
        for (int cf = 0; cf < 2; ++cf) acc[rf][cf] = (f32x4)0.f;

    #pragma unroll
    for (int kk = 0; kk < 8; ++kk) {
        const int kb = kk * 16 + g * 4;
        half4_t a[4];
        #pragma unroll
        for (int rf = 0; rf < 4; ++rf) {
            int r = r0 + rf * 16 + ln;
            int rr = r < nrows ? r : nrows - 1;
            float4 av = *(const float4*)(A + (size_t)rr * 128 + kb);
            a[rf] = cvt4(av.x, av.y, av.z, av.w);
        }
        #pragma unroll
        for (int cf = 0; cf < 2; ++cf) {
            int n = w * 32 + cf * 16 + ln;
            half4_t b = *(const half4_t*)(Bt + (size_t)n * 128 + kb);
            #pragma unroll
            for (int rf = 0; rf < 4; ++rf)
                acc[rf][cf] = __builtin_amdgcn_mfma_f32_16x16x16f16(a[rf], b, acc[rf][cf], 0, 0, 0);
        }
    }

    #pragma unroll
    for (int cf = 0; cf < 2; ++cf) {
        int n = w * 32 + cf * 16 + ln;
        float bv = bias ? bias[n] : 0.f;
        #pragma unroll
        for (int rf = 0; rf < 4; ++rf) {
            #pragma unroll
            for (int reg = 0; reg < 4; ++reg) {
                int r = r0 + rf * 16 + g * 4 + reg;
                if (r < nrows) {
                    float v = acc[rf][cf][reg] + bv;
                    if (mode == 2)      Ch[(size_t)r * 128 + n] = (half_t)v;
                    else if (mode == 1) C[(size_t)r * 128 + n] = sspf(v);
                    else                C[(size_t)r * 128 + n] = v;
                }
            }
        }
    }
}

// Fused edge pipeline, operand-swapped: per chunk of 128 edges, each of the
// 8 waves owns 16 edges end-to-end.
//  phase1: z[feat][edge] = W1^T @ f^T  (C-frag == phase-2 A-frag: no LDS roundtrip)
//  ssp in-register -> a2
//  phase2: O[edge][col] = a2 @ W2  (B frags from lane-linear LDS, conflict-free)
//  epilogue: (+b2)*rc*h[idx_j], 4-edge merged ds_add into bins
// ONE barrier per chunk; persistent block processes gpb groups of ATG atoms.
__global__ __launch_bounds__(512, 4) void edge_kernel(
    const float* __restrict__ f_ij, const float* __restrict__ rcut,
    const int* __restrict__ idx_i, const int* __restrict__ idx_j,
    const half_t* __restrict__ Wt_f1, const float* __restrict__ b_f1,
    const half_t* __restrict__ W2L, const float* __restrict__ b_f2,
    const half_t* __restrict__ hh, float* __restrict__ agg,
    const int* __restrict__ atom_start, int E, int N, int gpb)
{
    __shared__ __align__(16) half_t W2s[16384];          // 32768 B
    __shared__ __align__(16) half_t fsh[2][CHUNK][24];   // 12288 B
    __shared__ float bins[ATG][128];                     //  4096 B
    __shared__ int   jis[2][CHUNK];                      //  1024 B
    __shared__ int   ais[2][CHUNK];                      //  1024 B
    __shared__ float rcs[2][CHUNK];                      //  1024 B
    __shared__ float b1s[128];                           //   512 B

    const int tid = threadIdx.x;
    const int w = tid >> 6, l = tid & 63, g = l >> 4, ln = l & 15;

    const int nsg = (N + ATG - 1) / ATG;
    const int ga0 = blockIdx.x * gpb;
    if (ga0 >= nsg) return;
    const int gaE = min(ga0 + gpb, nsg);

    // one-time staging: W2 (lane-linear), b1, bins
    for (int i = tid; i < 2048; i += 512)
        ((float4*)W2s)[i] = ((const float4*)W2L)[i];
    if (tid < 128) b1s[tid] = b_f1[tid];
    for (int i = tid; i < ATG*128; i += 512) ((float*)&bins[0][0])[i] = 0.f;

    const int blo = atom_start[ga0 * ATG];
    const int bhi = atom_start[min(gaE * ATG, N)];

    float b2v[8];
    #pragma unroll
    for (int nt = 0; nt < 8; ++nt) b2v[nt] = b_f2[nt*16 + ln];

    // prologue: stage chunk 0 [blo, blo+128) into buffer 0 (direct)
    if (blo < bhi) {
        {
            int u = tid, e = blo + u/5;
            float4 v = make_float4(0.f,0.f,0.f,0.f);
            if (e < E) v = ((const float4*)f_ij)[(size_t)blo*5 + u];
            *(half4_t*)&fsh[0][u/5][(u%5)*4] = cvt4(v.x,v.y,v.z,v.w);
        }
        if (tid < 128) {
            int u = tid + 512, e = blo + u/5;
            float4 v = make_float4(0.f,0.f,0.f,0.f);
            if (e < E) v = ((const float4*)f_ij)[(size_t)blo*5 + u];
            *(half4_t*)&fsh[0][u/5][(u%5)*4] = cvt4(v.x,v.y,v.z,v.w);
            half4_t zz = {};
            *(half4_t*)&fsh[0][tid][20] = zz;   // zero-pad k=20..23
            int e2 = blo + tid; jis[0][tid] = (e2 < E) ? idx_j[e2] : 0;
        } else if (tid < 256) { int k = tid-128, e2 = blo+k; ais[0][k] = (e2<E)? idx_i[e2] : 0; }
        else if (tid < 384)   { int k = tid-256, e2 = blo+k; rcs[0][k] = (e2<E)? rcut[e2] : 0.f; }
    }
    __syncthreads();

    int p = 0;
    int cur = blo;
    for (int ga = ga0; ga < gaE; ++ga) {
        const int a0 = ga * ATG;
        const int ghi = atom_start[min(a0 + ATG, N)];
        while (cur < ghi) {
            const int chi = min(cur + CHUNK, ghi);
            const int nc0 = chi;                    // next chunk always starts at chi
            const bool stage = (nc0 < bhi);

            // ---- issue next-chunk staging loads (writes deferred) ----
            float4 fv0 = make_float4(0.f,0.f,0.f,0.f);
            float4 fv1 = make_float4(0.f,0.f,0.f,0.f);
            int mj = 0, ma = 0; float mr = 0.f;
            if (stage) {
                { int u = tid, e = nc0 + u/5;
                  if (e < E) fv0 = ((const float4*)f_ij)[(size_t)nc0*5 + u]; }
                if (tid < 128) {
                    int u = tid + 512, e = nc0 + u/5;
                    if (e < E) fv1 = ((const float4*)f_ij)[(size_t)nc0*5 + u];
                    int e2 = nc0 + tid; mj = (e2 < E) ? idx_j[e2] : 0;
                } else if (tid < 256) { int e2 = nc0+tid-128; ma = (e2<E)? idx_i[e2] : 0; }
                else if (tid < 384)   { int e2 = nc0+tid-256; mr = (e2<E)? rcut[e2] : 0.f; }
            }

            // ---- my 4 edges' j-indices; issue h loads half 1 (nt 0..3) ----
            int myji[4];
            #pragma unroll
            for (int r2 = 0; r2 < 4; ++r2)
                myji[r2] = jis[p][16*w + g*4 + r2];
            float hv0[4][4];
            #pragma unroll
            for (int q = 0; q < 4; ++q)
                #pragma unroll
                for (int r2 = 0; r2 < 4; ++r2)
                    hv0[q][r2] = (float)hh[(size_t)myji[r2]*128 + q*16 + ln];

            // ---- phase 1: z = W1^T @ f^T ----
            half4_t bfr0, bfr1;
            {
                const half_t* fr = &fsh[p][16*w + ln][0];
                bfr0 = *(const half4_t*)(fr + g*4);
                if (g < 2) bfr1 = *(const half4_t*)(fr + 16 + g*4);
                else { half4_t zz = {}; bfr1 = zz; }     // k>=24 doesn't exist
            }
            f32x4 z[8];
            #pragma unroll
            for (int rf = 0; rf < 8; ++rf) z[rf] = (f32x4)0.f;
            #pragma unroll
            for (int rf = 0; rf < 8; ++rf) {
                half4_t a0f = *(const half4_t*)(Wt_f1 + (size_t)(rf*16+ln)*32 + g*4);
                z[rf] = __builtin_amdgcn_mfma_f32_16x16x16f16(a0f, bfr0, z[rf], 0, 0, 0);
                half4_t a1f = *(const half4_t*)(Wt_f1 + (size_t)(rf*16+ln)*32 + 16 + g*4);
                z[rf] = __builtin_amdgcn_mfma_f32_16x16x16f16(a1f, bfr1, z[rf], 0, 0, 0);
            }

            // ---- ssp in-register -> phase-2 A fragments ----
            half4_t a2[8];
            #pragma unroll
            for (int rf = 0; rf < 8; ++rf) {
                float4 bb = *(const float4*)&b1s[rf*16 + g*4];
                a2[rf][0] = (half_t)sspf(z[rf][0] + bb.x);
                a2[rf][1] = (half_t)sspf(z[rf][1] + bb.y);
                a2[rf][2] = (half_t)sspf(z[rf][2] + bb.z);
                a2[rf][3] = (half_t)sspf(z[rf][3] + bb.w);
            }

            // ---- issue h loads half 2 (nt 4..7); epilogue metadata ----
            float hv1[4][4];
            #pragma unroll
            for (int q = 0; q < 4; ++q)
                #pragma unroll
                for (int r2 = 0; r2 < 4; ++r2)
                    hv1[q][r2] = (float)hh[(size_t)myji[r2]*128 + 64 + q*16 + ln];

            float myrc[4]; int mya[4];
            #pragma unroll
            for (int r2 = 0; r2 < 4; ++r2) {
                int ce = 16*w + g*4 + r2;
                bool val = (cur + ce) < chi;
                myrc[r2] = val ? rcs[p][ce] : 0.f;
                mya[r2]  = val ? (ais[p][ce] - a0) : 0;
            }
            const bool same = (mya[0] == mya[3]);   // sorted => all 4 equal

            // ---- phase 2 + fused epilogue, half 1 (nt 0..3) ----
            {
                f32x4 acc[4];
                #pragma unroll
                for (int q = 0; q < 4; ++q) acc[q] = (f32x4)0.f;
                #pragma unroll
                for (int kk = 0; kk < 8; ++kk)
                    #pragma unroll
                    for (int q = 0; q < 4; ++q) {
                        half4_t bw = *(const half4_t*)&W2s[(((kk*8+q)*4+g)*16+ln)*4];
                        acc[q] = __builtin_amdgcn_mfma_f32_16x16x16f16(a2[kk], bw, acc[q], 0, 0, 0);
                    }
                #pragma unroll
                for (int q = 0; q < 4; ++q) {
                    float bb = b2v[q];
                    if (same) {
                        float s = 0.f;
                        #pragma unroll
                        for (int r2 = 0; r2 < 4; ++r2)
                            s += (acc[q][r2] + bb) * myrc[r2] * hv0[q][r2];
                        atomicAdd(&bins[mya[0]][q*16+ln], s);
                    } else {
                        #pragma unroll
                        for (int r2 = 0; r2 < 4; ++r2)
                            atomicAdd(&bins[mya[r2]][q*16+ln],
                                      (acc[q][r2] + bb) * myrc[r2] * hv0[q][r2]);
                    }
                }
            }
            // ---- phase 2 + fused epilogue, half 2 (nt 4..7) ----
            {
                f32x4 acc[4];
                #pragma unroll
                for (int q = 0; q < 4; ++q) acc[q] = (f32x4)0.f;
                #pragma unroll
                for (int kk = 0; kk < 8; ++kk)
                    #pragma unroll
                    for (int q = 0; q < 4; ++q) {
                        int nt = 4 + q;
                        half4_t bw = *(const half4_t*)&W2s[(((kk*8+nt)*4+g)*16+ln)*4];
                        acc[q] = __builtin_amdgcn_mfma_f32_16x16x16f16(a2[kk], bw, acc[q], 0, 0, 0);
                    }
                #pragma unroll
                for (int q = 0; q < 4; ++q) {
                    int nt = 4 + q;
                    float bb = b2v[nt];
                    if (same) {
                        float s = 0.f;
                        #pragma unroll
                        for (int r2 = 0; r2 < 4; ++r2)
                            s += (acc[q][r2] + bb) * myrc[r2] * hv1[q][r2];
                        atomicAdd(&bins[mya[0]][nt*16+ln], s);
                    } else {
                        #pragma unroll
                        for (int r2 = 0; r2 < 4; ++r2)
                            atomicAdd(&bins[mya[r2]][nt*16+ln],
                                      (acc[q][r2] + bb) * myrc[r2] * hv1[q][r2]);
                    }
                }
            }

            // ---- deferred staging writes ----
            if (stage) {
                { int u = tid;
                  *(half4_t*)&fsh[p^1][u/5][(u%5)*4] = cvt4(fv0.x,fv0.y,fv0.z,fv0.w); }
                if (tid < 128) {
                    int u = tid + 512;
                    *(half4_t*)&fsh[p^1][u/5][(u%5)*4] = cvt4(fv1.x,fv1.y,fv1.z,fv1.w);
                    half4_t zz = {};
                    *(half4_t*)&fsh[p^1][tid][20] = zz;
                    jis[p^1][tid] = mj;
                } else if (tid < 256) ais[p^1][tid-128] = ma;
                else if (tid < 384)   rcs[p^1][tid-256] = mr;
            }
            __syncthreads();
            cur = chi; p ^= 1;
        }
        // ---- group writeout + bins re-zero ----
        __syncthreads();
        for (int i = tid; i < ATG*128; i += 512) {
            int at = i >> 7, c = i & 127;
            int arow = a0 + at;
            float v = bins[at][c];
            if (arow < N) agg[(size_t)arow*128 + c] = v;
            bins[at][c] = 0.f;
        }
        __syncthreads();
    }
}

extern "C" void kernel_launch(void* const* d_in, const int* in_sizes, int n_in,
                              void* d_out, int out_size, void* d_ws, size_t ws_size,
                              hipStream_t stream)
{
    const float* x      = (const float*)d_in[0];
    const float* f_ij   = (const float*)d_in[1];
    const float* rcut   = (const float*)d_in[2];
    const int*   idx_i  = (const int*)d_in[3];
    const int*   idx_j  = (const int*)d_in[4];
    const float* W_in2f = (const float*)d_in[5];
    const float* W_f1   = (const float*)d_in[6];
    const float* b_f1   = (const float*)d_in[7];
    const float* W_f2   = (const float*)d_in[8];
    const float* b_f2   = (const float*)d_in[9];
    const float* W_o1   = (const float*)d_in[10];
    const float* b_o1   = (const float*)d_in[11];
    const float* W_o2   = (const float*)d_in[12];
    const float* b_o2   = (const float*)d_in[13];

    const int N = in_sizes[0] / 128;
    const int E = in_sizes[2];

    // ws layout: h as f16 (aliases later t-f32 buffer), then weights
    half_t* h16  = (half_t*)d_ws;                       // [N,128] f16
    float*  tbuf = (float*)d_ws;                        // [N,128] f32 (after edge)
    half_t* wt   = (half_t*)((char*)d_ws + (size_t)N * 128 * 4);
    half_t* Wt_in2f = wt;                 // 16384 halfs
    half_t* Wt_f1   = wt + 16384;         //  4096
    half_t* W2L     = wt + 16384 + 4096;  // 16384 (lane-linear W_f2)
    half_t* Wt_o1   = W2L + 16384;        // 16384
    half_t* Wt_o2   = Wt_o1 + 16384;      // 16384
    int* atom_start = (int*)(Wt_o2 + 16384);            // N+1 ints

    prep_weights<<<272, 256, 0, stream>>>(W_in2f, W_f1, W_f2, W_o1, W_o2,
                                          Wt_in2f, Wt_f1, W2L, Wt_o1, Wt_o2);
    seg_starts<<<(E + 255) / 256, 256, 0, stream>>>(idx_i, atom_start, E, N);

    const int gn  = (N + 63) / 64;
    const int nsg = (N + ATG - 1) / ATG;
    const int gpb = 5;
    const int nbl = (nsg + gpb - 1) / gpb;

    // h = x @ W_in2f  -> f16
    mfma_gemm<<<gn, 256, 0, stream>>>(x, Wt_in2f, nullptr, nullptr, h16, N, 2);

    // fused edge pipeline -> agg rows (full overwrite of d_out)
    edge_kernel<<<nbl, 512, 0, stream>>>(f_ij, rcut, idx_i, idx_j,
                                         Wt_f1, b_f1, W2L, b_f2,
                                         h16, (float*)d_out, atom_start, E, N, gpb);

    // t = ssp(agg @ W_o1 + b_o1)
    mfma_gemm<<<gn, 256, 0, stream>>>((const float*)d_out, Wt_o1, b_o1, tbuf, nullptr, N, 1);

    // out = t @ W_o2 + b_o2
    mfma_gemm<<<gn, 256, 0, stream>>>(tbuf, Wt_o2, b_o2, (float*)d_out, nullptr, N, 0);
}

// Round 6
// 887.809 us; speedup vs baseline: 1.1148x; 1.1148x over previous
//
#include <hip/hip_runtime.h>
#include <math.h>

#define LN2F 0.6931471805599453f
#define ATG 12
#define CHUNK 128

typedef _Float16 half_t;
typedef _Float16 half4_t __attribute__((ext_vector_type(4)));
typedef float f32x4 __attribute__((ext_vector_type(4)));

__device__ __forceinline__ float sspf(float z) {
    // ssp(z) = max(z,0) + log(1+exp(-|z|)) - ln2   (fast HW intrinsics)
    return fmaxf(z, 0.f) + __logf(1.f + __expf(-fabsf(z))) - LN2F;
}
__device__ __forceinline__ half4_t cvt4(float x, float y, float z, float w) {
    half4_t r; r[0]=(half_t)x; r[1]=(half_t)y; r[2]=(half_t)z; r[3]=(half_t)w; return r;
}

// Weight prep (one launch):
//  Wt_in2f/Wt_o1/Wt_o2: dst[n*128+k] = W[k][n]  (f16, mfma_gemm B)
//  Wt_f1: dst[n*32+k] = W_f1[k][n], k<20 else 0  (kept for layout compat; unused)
//  W2L: lane-linear layout for edge phase-2 B frags:
//       W2L[(((kk*8+nt)*4+g)*16+ln)*4 + j] = W_f2[kk*16+g*4+j][nt*16+ln]
__global__ __launch_bounds__(256) void prep_weights(
    const float* __restrict__ W_in2f, const float* __restrict__ W_f1,
    const float* __restrict__ W_f2, const float* __restrict__ W_o1,
    const float* __restrict__ W_o2,
    half_t* __restrict__ Wt_in2f, half_t* __restrict__ Wt_f1,
    half_t* __restrict__ W2L, half_t* __restrict__ Wt_o1,
    half_t* __restrict__ Wt_o2)
{
    int b = blockIdx.x;
    if (b < 64) {
        int i = b*256 + threadIdx.x;
        Wt_in2f[i] = (half_t)W_in2f[(i & 127)*128 + (i >> 7)];
    } else if (b < 80) {
        int i = (b-64)*256 + threadIdx.x;
        int n = i >> 5, k = i & 31;
        Wt_f1[i] = (k < 20) ? (half_t)W_f1[k*128 + n] : (half_t)0.f;
    } else if (b < 144) {
        int hidx = (b-80)*256 + threadIdx.x;
        int j = hidx & 3, i4 = hidx >> 2;
        int ln = i4 & 15, g = (i4 >> 4) & 3, nt = (i4 >> 6) & 7, kk = i4 >> 9;
        W2L[hidx] = (half_t)W_f2[(kk*16 + g*4 + j)*128 + nt*16 + ln];
    } else if (b < 208) {
        int i = (b-144)*256 + threadIdx.x;
        Wt_o1[i] = (half_t)W_o1[(i & 127)*128 + (i >> 7)];
    } else {
        int i = (b-208)*256 + threadIdx.x;
        Wt_o2[i] = (half_t)W_o2[(i & 127)*128 + (i >> 7)];
    }
}

// atom_start[a] = first edge index with idx_i >= a; atom_start[N] = E
__global__ __launch_bounds__(256) void seg_starts(
    const int* __restrict__ idx_i, int* __restrict__ atom_start, int E, int N)
{
    int e = blockIdx.x * 256 + threadIdx.x;
    if (e >= E) return;
    int a = idx_i[e];
    int prev = (e == 0) ? -1 : idx_i[e - 1];
    for (int k = prev + 1; k <= a; ++k) atom_start[k] = e;
    if (e == E - 1)
        for (int k = a + 1; k <= N; ++k) atom_start[k] = E;
}

// C = act(A @ B + bias); A:[nrows,128] f32, Bt f16 (Bt[n][k]=B[k][n])
// mode: 0 = f32 out, 1 = f32 out + ssp, 2 = f16 out (Ch)
__global__ __launch_bounds__(256) void mfma_gemm(
    const float* __restrict__ A, const half_t* __restrict__ Bt,
    const float* __restrict__ bias, float* __restrict__ C,
    half_t* __restrict__ Ch, int nrows, int mode)
{
    const int tid = threadIdx.x;
    const int w = tid >> 6, l = tid & 63, g = l >> 4, ln = l & 15;
    const int r0 = blockIdx.x * 64;

    f32x4 acc[4][2];
    #pragma unroll
    for (int rf = 0; rf < 4; ++rf)
        #pragma unroll
        for (int cf = 0; cf < 2; ++cf) acc[rf][cf] = (f32x4)0.f;

    #pragma unroll
    for (int kk = 0; kk < 8; ++kk) {
        const int kb = kk * 16 + g * 4;
        half4_t a[4];
        #pragma unroll
        for (int rf = 0; rf < 4; ++rf) {
            int r = r0 + rf * 16 + ln;
            int rr = r < nrows ? r : nrows - 1;
            float4 av = *(const float4*)(A + (size_t)rr * 128 + kb);
            a[rf] = cvt4(av.x, av.y, av.z, av.w);
        }
        #pragma unroll
        for (int cf = 0; cf < 2; ++cf) {
            int n = w * 32 + cf * 16 + ln;
            half4_t b = *(const half4_t*)(Bt + (size_t)n * 128 + kb);
            #pragma unroll
            for (int rf = 0; rf < 4; ++rf)
                acc[rf][cf] = __builtin_amdgcn_mfma_f32_16x16x16f16(a[rf], b, acc[rf][cf], 0, 0, 0);
        }
    }

    #pragma unroll
    for (int cf = 0; cf < 2; ++cf) {
        int n = w * 32 + cf * 16 + ln;
        float bv = bias ? bias[n] : 0.f;
        #pragma unroll
        for (int rf = 0; rf < 4; ++rf) {
            #pragma unroll
            for (int reg = 0; reg < 4; ++reg) {
                int r = r0 + rf * 16 + g * 4 + reg;
                if (r < nrows) {
                    float v = acc[rf][cf][reg] + bv;
                    if (mode == 2)      Ch[(size_t)r * 128 + n] = (half_t)v;
                    else if (mode == 1) C[(size_t)r * 128 + n] = sspf(v);
                    else                C[(size_t)r * 128 + n] = v;
                }
            }
        }
    }
}

// Fused edge pipeline, operand-swapped + coalesced h staging.
// Per 128-edge chunk, each of 8 waves owns 16 edges end-to-end:
//   phase1: z[feat][edge] = W1^T @ f^T (A from LDS W1s, B from prefetched regs)
//   ssp in-register -> a2 (phase-2 A frags, no LDS roundtrip)
//   phase2: O[edge][col] = a2 @ W2 (B from lane-linear LDS W2s, conflict-free)
//   epilogue: (+b2)*rc*h (h from coalesced-staged hsh), merged ds_add to bins
// h rows / f_ij prefetched one chunk ahead into registers. 2 barriers/chunk.
__global__ __launch_bounds__(512, 4) void edge_kernel(
    const float* __restrict__ f_ij, const float* __restrict__ rcut,
    const int* __restrict__ idx_i, const int* __restrict__ idx_j,
    const float* __restrict__ W_f1, const float* __restrict__ b_f1,
    const half_t* __restrict__ W2L, const float* __restrict__ b_f2,
    const half_t* __restrict__ hh, float* __restrict__ agg,
    const int* __restrict__ atom_start, int E, int N, int gpb)
{
    __shared__ __align__(16) half_t W2s[16384];        // 32768 B
    __shared__ __align__(16) half_t hsh[CHUNK][136];   // 34816 B
    __shared__ __align__(16) half_t W1s[128][24];      //  6144 B
    __shared__ float bins[ATG][128];                   //  6144 B
    __shared__ float b1s[128];                         //   512 B
    // total 80384 B -> 2 blocks/CU

    const int tid = threadIdx.x;
    const int w = tid >> 6, l = tid & 63, g = l >> 4, ln = l & 15;

    const int nsg = (N + ATG - 1) / ATG;
    const int ga0 = blockIdx.x * gpb;
    if (ga0 >= nsg) return;
    const int gaE = min(ga0 + gpb, nsg);

    // one-time staging
    for (int i = tid; i < 2048; i += 512)
        ((float4*)W2s)[i] = ((const float4*)W2L)[i];
    for (int i = tid; i < 128*24; i += 512) {
        int f = i / 24, k = i - f*24;
        W1s[f][k] = (k < 20) ? (half_t)W_f1[k*128 + f] : (half_t)0.f;
    }
    if (tid < 128) b1s[tid] = b_f1[tid];
    for (int i = tid; i < ATG*128; i += 512) ((float*)&bins[0][0])[i] = 0.f;

    const int blo = atom_start[ga0 * ATG];
    const int bhi = atom_start[min(gaE * ATG, N)];

    float b2v[8];
    #pragma unroll
    for (int nt = 0; nt < 8; ++nt) b2v[nt] = b_f2[nt*16 + ln];

    const int hrow = tid >> 4;   // 0..31 (+32*it)
    const int hseg = tid & 15;

    // ---- prologue: issue chunk-0 loads ----
    int jv[4];
    float4 hpre[4];
    float4 fA = make_float4(0.f,0.f,0.f,0.f), fB = make_float4(0.f,0.f,0.f,0.f);
    if (blo < bhi) {
        #pragma unroll
        for (int it = 0; it < 4; ++it) {
            int r = blo + hrow + 32*it;
            jv[it] = (r < E) ? idx_j[r] : 0;
        }
        #pragma unroll
        for (int it = 0; it < 4; ++it)
            hpre[it] = *(const float4*)(hh + (size_t)jv[it]*128 + hseg*8);
        int e = blo + 16*w + ln;
        if (e < E) {
            fA = *(const float4*)(f_ij + (size_t)e*20 + g*4);
            if (g == 0) fB = *(const float4*)(f_ij + (size_t)e*20 + 16);
        }
    }

    int cur = blo;
    for (int ga = ga0; ga < gaE; ++ga) {
        const int a0 = ga * ATG;
        const int ghi = atom_start[min(a0 + ATG, N)];
        while (cur < ghi) {
            const int chi = min(cur + CHUNK, ghi);
            const int nc = chi;
            const bool stage = (nc < bhi);

            __syncthreads();                           // B1: prev epilogue done

            // hsh <- current chunk's h rows (loads issued last chunk)
            #pragma unroll
            for (int it = 0; it < 4; ++it)
                *(float4*)&hsh[hrow + 32*it][hseg*8] = hpre[it];

            // issue next-chunk idx_j
            if (stage) {
                #pragma unroll
                for (int it = 0; it < 4; ++it) {
                    int r = nc + hrow + 32*it;
                    jv[it] = (r < E) ? idx_j[r] : 0;
                }
            }
            // current-chunk epilogue metadata (broadcast loads)
            float rcv[4]; int aiv[4];
            #pragma unroll
            for (int r2 = 0; r2 < 4; ++r2) {
                int e = cur + 16*w + 4*g + r2;
                bool val = e < chi;
                rcv[r2] = val ? rcut[e] : 0.f;
                aiv[r2] = val ? (idx_i[e] - a0) : 0;
            }

            // ---- phase 1: z = W1^T @ f^T ----
            half4_t bfr0 = cvt4(fA.x, fA.y, fA.z, fA.w);
            half4_t bfr1;
            if (g == 0) bfr1 = cvt4(fB.x, fB.y, fB.z, fB.w);
            else { half4_t zz = {}; bfr1 = zz; }
            f32x4 z[8];
            #pragma unroll
            for (int rf = 0; rf < 8; ++rf) z[rf] = (f32x4)0.f;
            #pragma unroll
            for (int rf = 0; rf < 8; ++rf) {
                half4_t a0f = *(const half4_t*)&W1s[rf*16 + ln][g*4];
                z[rf] = __builtin_amdgcn_mfma_f32_16x16x16f16(a0f, bfr0, z[rf], 0, 0, 0);
                half4_t a1f;
                if (g == 0) a1f = *(const half4_t*)&W1s[rf*16 + ln][16];
                else { half4_t zz = {}; a1f = zz; }
                z[rf] = __builtin_amdgcn_mfma_f32_16x16x16f16(a1f, bfr1, z[rf], 0, 0, 0);
            }

            // issue next-chunk f_ij prefetch
            if (stage) {
                int e = nc + 16*w + ln;
                fA = make_float4(0.f,0.f,0.f,0.f);
                fB = make_float4(0.f,0.f,0.f,0.f);
                if (e < E) {
                    fA = *(const float4*)(f_ij + (size_t)e*20 + g*4);
                    if (g == 0) fB = *(const float4*)(f_ij + (size_t)e*20 + 16);
                }
            }

            // ---- ssp in-register -> phase-2 A fragments ----
            half4_t a2[8];
            #pragma unroll
            for (int rf = 0; rf < 8; ++rf) {
                float4 bb = *(const float4*)&b1s[rf*16 + g*4];
                a2[rf][0] = (half_t)sspf(z[rf][0] + bb.x);
                a2[rf][1] = (half_t)sspf(z[rf][1] + bb.y);
                a2[rf][2] = (half_t)sspf(z[rf][2] + bb.z);
                a2[rf][3] = (half_t)sspf(z[rf][3] + bb.w);
            }

            // issue next-chunk h loads (jv arrived during phase 1)
            if (stage) {
                #pragma unroll
                for (int it = 0; it < 4; ++it)
                    hpre[it] = *(const float4*)(hh + (size_t)jv[it]*128 + hseg*8);
            }

            const bool same = (aiv[0] == aiv[3]);

            // ---- phase 2 half 1 (nt = 0..3) ----
            f32x4 acc[4];
            #pragma unroll
            for (int q = 0; q < 4; ++q) acc[q] = (f32x4)0.f;
            #pragma unroll
            for (int kk = 0; kk < 8; ++kk)
                #pragma unroll
                for (int q = 0; q < 4; ++q) {
                    half4_t bw = *(const half4_t*)&W2s[(((kk*8+q)*4+g)*16+ln)*4];
                    acc[q] = __builtin_amdgcn_mfma_f32_16x16x16f16(a2[kk], bw, acc[q], 0, 0, 0);
                }

            __syncthreads();                           // B2: hsh visible

            // epilogue half 1
            #pragma unroll
            for (int q = 0; q < 4; ++q) {
                float bb = b2v[q];
                if (same) {
                    float s = 0.f;
                    #pragma unroll
                    for (int r2 = 0; r2 < 4; ++r2)
                        s += (acc[q][r2] + bb) * rcv[r2] * (float)hsh[16*w+4*g+r2][q*16+ln];
                    atomicAdd(&bins[aiv[0]][q*16+ln], s);
                } else {
                    #pragma unroll
                    for (int r2 = 0; r2 < 4; ++r2)
                        atomicAdd(&bins[aiv[r2]][q*16+ln],
                                  (acc[q][r2] + bb) * rcv[r2] * (float)hsh[16*w+4*g+r2][q*16+ln]);
                }
            }

            // ---- phase 2 half 2 (nt = 4..7) ----
            #pragma unroll
            for (int q = 0; q < 4; ++q) acc[q] = (f32x4)0.f;
            #pragma unroll
            for (int kk = 0; kk < 8; ++kk)
                #pragma unroll
                for (int q = 0; q < 4; ++q) {
                    int nt = 4 + q;
                    half4_t bw = *(const half4_t*)&W2s[(((kk*8+nt)*4+g)*16+ln)*4];
                    acc[q] = __builtin_amdgcn_mfma_f32_16x16x16f16(a2[kk], bw, acc[q], 0, 0, 0);
                }
            // epilogue half 2
            #pragma unroll
            for (int q = 0; q < 4; ++q) {
                int nt = 4 + q;
                float bb = b2v[nt];
                if (same) {
                    float s = 0.f;
                    #pragma unroll
                    for (int r2 = 0; r2 < 4; ++r2)
                        s += (acc[q][r2] + bb) * rcv[r2] * (float)hsh[16*w+4*g+r2][nt*16+ln];
                    atomicAdd(&bins[aiv[0]][nt*16+ln], s);
                } else {
                    #pragma unroll
                    for (int r2 = 0; r2 < 4; ++r2)
                        atomicAdd(&bins[aiv[r2]][nt*16+ln],
                                  (acc[q][r2] + bb) * rcv[r2] * (float)hsh[16*w+4*g+r2][nt*16+ln]);
                }
            }

            cur = chi;
        }
        // ---- group writeout + bins re-zero ----
        __syncthreads();
        for (int i = tid; i < ATG*128; i += 512) {
            int at = i >> 7, c = i & 127;
            int arow = a0 + at;
            float v = bins[at][c];
            if (arow < N) agg[(size_t)arow*128 + c] = v;
            bins[at][c] = 0.f;
        }
    }
}

extern "C" void kernel_launch(void* const* d_in, const int* in_sizes, int n_in,
                              void* d_out, int out_size, void* d_ws, size_t ws_size,
                              hipStream_t stream)
{
    const float* x      = (const float*)d_in[0];
    const float* f_ij   = (const float*)d_in[1];
    const float* rcut   = (const float*)d_in[2];
    const int*   idx_i  = (const int*)d_in[3];
    const int*   idx_j  = (const int*)d_in[4];
    const float* W_in2f = (const float*)d_in[5];
    const float* W_f1   = (const float*)d_in[6];
    const float* b_f1   = (const float*)d_in[7];
    const float* W_f2   = (const float*)d_in[8];
    const float* b_f2   = (const float*)d_in[9];
    const float* W_o1   = (const float*)d_in[10];
    const float* b_o1   = (const float*)d_in[11];
    const float* W_o2   = (const float*)d_in[12];
    const float* b_o2   = (const float*)d_in[13];

    const int N = in_sizes[0] / 128;
    const int E = in_sizes[2];

    // ws layout: h as f16 (aliases later t-f32 buffer), then weights
    half_t* h16  = (half_t*)d_ws;                       // [N,128] f16
    float*  tbuf = (float*)d_ws;                        // [N,128] f32 (after edge)
    half_t* wt   = (half_t*)((char*)d_ws + (size_t)N * 128 * 4);
    half_t* Wt_in2f = wt;                 // 16384 halfs
    half_t* Wt_f1   = wt + 16384;         //  4096 (unused by edge, layout compat)
    half_t* W2L     = wt + 16384 + 4096;  // 16384 (lane-linear W_f2)
    half_t* Wt_o1   = W2L + 16384;        // 16384
    half_t* Wt_o2   = Wt_o1 + 16384;      // 16384
    int* atom_start = (int*)(Wt_o2 + 16384);            // N+1 ints

    prep_weights<<<272, 256, 0, stream>>>(W_in2f, W_f1, W_f2, W_o1, W_o2,
                                          Wt_in2f, Wt_f1, W2L, Wt_o1, Wt_o2);
    seg_starts<<<(E + 255) / 256, 256, 0, stream>>>(idx_i, atom_start, E, N);

    const int gn  = (N + 63) / 64;
    const int nsg = (N + ATG - 1) / ATG;
    const int gpb = 4;
    const int nbl = (nsg + gpb - 1) / gpb;

    // h = x @ W_in2f  -> f16
    mfma_gemm<<<gn, 256, 0, stream>>>(x, Wt_in2f, nullptr, nullptr, h16, N, 2);

    // fused edge pipeline -> agg rows (full overwrite of d_out)
    edge_kernel<<<nbl, 512, 0, stream>>>(f_ij, rcut, idx_i, idx_j,
                                         W_f1, b_f1, W2L, b_f2,
                                         h16, (float*)d_out, atom_start, E, N, gpb);

    // t = ssp(agg @ W_o1 + b_o1)
    mfma_gemm<<<gn, 256, 0, stream>>>((const float*)d_out, Wt_o1, b_o1, tbuf, nullptr, N, 1);

    // out = t @ W_o2 + b_o2
    mfma_gemm<<<gn, 256, 0, stream>>>(tbuf, Wt_o2, b_o2, (float*)d_out, nullptr, N, 0);
}

// Round 7
// 769.735 us; speedup vs baseline: 1.2858x; 1.1534x over previous
//
#include <hip/hip_runtime.h>
#include <math.h>

#define LN2F 0.6931471805599453f
#define ATG 16
#define CHUNK 128

typedef _Float16 half_t;
typedef _Float16 half4_t __attribute__((ext_vector_type(4)));
typedef float f32x4 __attribute__((ext_vector_type(4)));

__device__ __forceinline__ float sspf(float z) {
    // ssp(z) = max(z,0) + log(1+exp(-|z|)) - ln2   (fast HW intrinsics)
    return fmaxf(z, 0.f) + __logf(1.f + __expf(-fabsf(z))) - LN2F;
}
__device__ __forceinline__ half4_t cvt4(float x, float y, float z, float w) {
    half4_t r; r[0]=(half_t)x; r[1]=(half_t)y; r[2]=(half_t)z; r[3]=(half_t)w; return r;
}

// async global->LDS DMA, 16 B per lane; un-sinkable (side effect), drained by
// the vmcnt(0) inside __syncthreads().
__device__ __forceinline__ void load_lds16(const void* g, void* l) {
    __builtin_amdgcn_global_load_lds(
        (const __attribute__((address_space(1))) unsigned int*)g,
        (__attribute__((address_space(3))) unsigned int*)l, 16, 0, 0);
}

// Weight prep (one launch):
//  Wt_in2f/Wt_o1/Wt_o2: dst[n*128+k] = W[k][n]  (f16, mfma_gemm B)
//  Wt_f1: dst[n*32+k] = W_f1[k][n], k<20 else 0  (layout compat; unused by edge)
//  W2L: lane-linear layout for edge phase-2 B frags:
//       W2L[(((kk*8+nt)*4+g)*16+ln)*4 + j] = W_f2[kk*16+g*4+j][nt*16+ln]
__global__ __launch_bounds__(256) void prep_weights(
    const float* __restrict__ W_in2f, const float* __restrict__ W_f1,
    const float* __restrict__ W_f2, const float* __restrict__ W_o1,
    const float* __restrict__ W_o2,
    half_t* __restrict__ Wt_in2f, half_t* __restrict__ Wt_f1,
    half_t* __restrict__ W2L, half_t* __restrict__ Wt_o1,
    half_t* __restrict__ Wt_o2)
{
    int b = blockIdx.x;
    if (b < 64) {
        int i = b*256 + threadIdx.x;
        Wt_in2f[i] = (half_t)W_in2f[(i & 127)*128 + (i >> 7)];
    } else if (b < 80) {
        int i = (b-64)*256 + threadIdx.x;
        int n = i >> 5, k = i & 31;
        Wt_f1[i] = (k < 20) ? (half_t)W_f1[k*128 + n] : (half_t)0.f;
    } else if (b < 144) {
        int hidx = (b-80)*256 + threadIdx.x;
        int j = hidx & 3, i4 = hidx >> 2;
        int ln = i4 & 15, g = (i4 >> 4) & 3, nt = (i4 >> 6) & 7, kk = i4 >> 9;
        W2L[hidx] = (half_t)W_f2[(kk*16 + g*4 + j)*128 + nt*16 + ln];
    } else if (b < 208) {
        int i = (b-144)*256 + threadIdx.x;
        Wt_o1[i] = (half_t)W_o1[(i & 127)*128 + (i >> 7)];
    } else {
        int i = (b-208)*256 + threadIdx.x;
        Wt_o2[i] = (half_t)W_o2[(i & 127)*128 + (i >> 7)];
    }
}

// atom_start[a] = first edge index with idx_i >= a; atom_start[N] = E
__global__ __launch_bounds__(256) void seg_starts(
    const int* __restrict__ idx_i, int* __restrict__ atom_start, int E, int N)
{
    int e = blockIdx.x * 256 + threadIdx.x;
    if (e >= E) return;
    int a = idx_i[e];
    int prev = (e == 0) ? -1 : idx_i[e - 1];
    for (int k = prev + 1; k <= a; ++k) atom_start[k] = e;
    if (e == E - 1)
        for (int k = a + 1; k <= N; ++k) atom_start[k] = E;
}

// C = act(A @ B + bias); A:[nrows,128] f32, Bt f16 (Bt[n][k]=B[k][n])
// mode: 0 = f32 out, 1 = f32 out + ssp, 2 = f16 out (Ch)
__global__ __launch_bounds__(256) void mfma_gemm(
    const float* __restrict__ A, const half_t* __restrict__ Bt,
    const float* __restrict__ bias, float* __restrict__ C,
    half_t* __restrict__ Ch, int nrows, int mode)
{
    const int tid = threadIdx.x;
    const int w = tid >> 6, l = tid & 63, g = l >> 4, ln = l & 15;
    const int r0 = blockIdx.x * 64;

    f32x4 acc[4][2];
    #pragma unroll
    for (int rf = 0; rf < 4; ++rf)
        #pragma unroll
        for (int cf = 0; cf < 2; ++cf) acc[rf][cf] = (f32x4)0.f;

    #pragma unroll
    for (int kk = 0; kk < 8; ++kk) {
        const int kb = kk * 16 + g * 4;
        half4_t a[4];
        #pragma unroll
        for (int rf = 0; rf < 4; ++rf) {
            int r = r0 + rf * 16 + ln;
            int rr = r < nrows ? r : nrows - 1;
            float4 av = *(const float4*)(A + (size_t)rr * 128 + kb);
            a[rf] = cvt4(av.x, av.y, av.z, av.w);
        }
        #pragma unroll
        for (int cf = 0; cf < 2; ++cf) {
            int n = w * 32 + cf * 16 + ln;
            half4_t b = *(const half4_t*)(Bt + (size_t)n * 128 + kb);
            #pragma unroll
            for (int rf = 0; rf < 4; ++rf)
                acc[rf][cf] = __builtin_amdgcn_mfma_f32_16x16x16f16(a[rf], b, acc[rf][cf], 0, 0, 0);
        }
    }

    #pragma unroll
    for (int cf = 0; cf < 2; ++cf) {
        int n = w * 32 + cf * 16 + ln;
        float bv = bias ? bias[n] : 0.f;
        #pragma unroll
        for (int rf = 0; rf < 4; ++rf) {
            #pragma unroll
            for (int reg = 0; reg < 4; ++reg) {
                int r = r0 + rf * 16 + g * 4 + reg;
                if (r < nrows) {
                    float v = acc[rf][cf][reg] + bv;
                    if (mode == 2)      Ch[(size_t)r * 128 + n] = (half_t)v;
                    else if (mode == 1) C[(size_t)r * 128 + n] = sspf(v);
                    else                C[(size_t)r * 128 + n] = v;
                }
            }
        }
    }
}

// Fused edge pipeline. Per 128-edge chunk, 8 waves x 16 edges each:
//   phase1: z = W1^T @ f^T (operand-swap; C-frag == phase-2 A-frag)
//   ssp in-register -> a2
//   phase2: O = a2 @ W2 (B frags from lane-linear LDS, conflict-free)
//   epilogue: (+b2)*rc*h (h via global_load_lds DMA, XOR-swizzled), ds_add bins
// Pipeline enforcement: h staging uses global_load_lds (un-sinkable DMA,
// drained by __syncthreads); register prefetches pinned by asm memory fences.
__global__ __launch_bounds__(512, 4) void edge_kernel(
    const float* __restrict__ f_ij, const float* __restrict__ rcut,
    const int* __restrict__ idx_i, const int* __restrict__ idx_j,
    const float* __restrict__ W_f1, const float* __restrict__ b_f1,
    const half_t* __restrict__ W2L, const float* __restrict__ b_f2,
    const half_t* __restrict__ hh, float* __restrict__ agg,
    const int* __restrict__ atom_start, int E, int N, int gpb)
{
    __shared__ __align__(16) half_t W2s[16384];      // 32768 B
    __shared__ __align__(16) half_t hsh[CHUNK*128];  // 32768 B (seg-swizzled)
    __shared__ __align__(16) half_t W1s[128][24];    //  6144 B
    __shared__ float bins[ATG][128];                 //  8192 B
    __shared__ float b1s[128];                       //   512 B
    // total 80384 B -> 2 blocks/CU

    const int tid = threadIdx.x;
    const int w = tid >> 6, l = tid & 63, g = l >> 4, ln = l & 15;
    const int lnhi = ln >> 3, lnlo = ln & 7;

    const int nsg = (N + ATG - 1) / ATG;
    const int ga0 = blockIdx.x * gpb;
    if (ga0 >= nsg) return;
    const int gaE = min(ga0 + gpb, nsg);

    // one-time staging
    for (int i = tid; i < 2048; i += 512)
        ((float4*)W2s)[i] = ((const float4*)W2L)[i];
    for (int i = tid; i < 128*24; i += 512) {
        int f = i / 24, k = i - f*24;
        W1s[f][k] = (k < 20) ? (half_t)W_f1[k*128 + f] : (half_t)0.f;
    }
    if (tid < 128) b1s[tid] = b_f1[tid];
    for (int i = tid; i < ATG*128; i += 512) ((float*)&bins[0][0])[i] = 0.f;

    const int blo = atom_start[ga0 * ATG];
    const int bhi = atom_start[min(gaE * ATG, N)];

    float b2v[8];
    #pragma unroll
    for (int nt = 0; nt < 8; ++nt) b2v[nt] = b_f2[nt*16 + ln];

    // ---- prologue: prefetch chunk 0 (jv for h-DMA; fA/fB for phase1) ----
    int jv[4];
    float4 fA = make_float4(0.f,0.f,0.f,0.f), fB = make_float4(0.f,0.f,0.f,0.f);
    if (blo < bhi) {
        #pragma unroll
        for (int it = 0; it < 4; ++it) {
            int r = blo + 4*w + 32*it + g;       // row this lane serves in h-DMA
            jv[it] = (r < E) ? idx_j[r] : 0;
        }
        int e = blo + 16*w + ln;
        if (e < E) {
            fA = *(const float4*)(f_ij + (size_t)e*20 + g*4);
            if (g == 0) fB = *(const float4*)(f_ij + (size_t)e*20 + 16);
        }
    }
    asm volatile("" ::: "memory");   // pin prefetch issue point

    const int brow = 16*w + 4*g;     // this thread's first edge-row in hsh

    int cur = blo;
    for (int ga = ga0; ga < gaE; ++ga) {
        const int a0 = ga * ATG;
        const int ghi = atom_start[min(a0 + ATG, N)];
        while (cur < ghi) {
            const int chi = min(cur + CHUNK, ghi);
            const int nc = chi;
            const bool stage = (nc < bhi);

            __syncthreads();   // B1: hsh free (prev epilogue done), prefetches landed

            // ---- h DMA for current chunk (XOR seg-swizzle, linear LDS dest) ----
            #pragma unroll
            for (int it = 0; it < 4; ++it) {
                const int M = (w + 8*it) & 3;                 // = (dest_row>>2)&3
                load_lds16(hh + (size_t)jv[it]*128 + ((ln ^ M) << 3),
                           &hsh[(4*w + 32*it) * 128]);
            }
            // current-chunk epilogue metadata (16-lane broadcast loads)
            float rcv[4]; int aiv[4];
            #pragma unroll
            for (int r2 = 0; r2 < 4; ++r2) {
                int e = cur + brow + r2;
                bool val = e < chi;
                rcv[r2] = val ? rcut[e] : 0.f;
                aiv[r2] = val ? (idx_i[e] - a0) : 0;
            }
            asm volatile("" ::: "memory");   // pin metadata issue before phase1

            // ---- phase 1: z = W1^T @ f^T ----
            half4_t bfr0 = cvt4(fA.x, fA.y, fA.z, fA.w);
            half4_t bfr1;
            if (g == 0) bfr1 = cvt4(fB.x, fB.y, fB.z, fB.w);
            else { half4_t zz = {}; bfr1 = zz; }
            f32x4 z[8];
            #pragma unroll
            for (int rf = 0; rf < 8; ++rf) z[rf] = (f32x4)0.f;
            #pragma unroll
            for (int rf = 0; rf < 8; ++rf) {
                half4_t a0f = *(const half4_t*)&W1s[rf*16 + ln][g*4];
                z[rf] = __builtin_amdgcn_mfma_f32_16x16x16f16(a0f, bfr0, z[rf], 0, 0, 0);
                half4_t a1f;
                if (g == 0) a1f = *(const half4_t*)&W1s[rf*16 + ln][16];
                else { half4_t zz = {}; a1f = zz; }
                z[rf] = __builtin_amdgcn_mfma_f32_16x16x16f16(a1f, bfr1, z[rf], 0, 0, 0);
            }

            // ---- ssp in-register -> phase-2 A fragments ----
            half4_t a2[8];
            #pragma unroll
            for (int rf = 0; rf < 8; ++rf) {
                float4 bb = *(const float4*)&b1s[rf*16 + g*4];
                a2[rf][0] = (half_t)sspf(z[rf][0] + bb.x);
                a2[rf][1] = (half_t)sspf(z[rf][1] + bb.y);
                a2[rf][2] = (half_t)sspf(z[rf][2] + bb.z);
                a2[rf][3] = (half_t)sspf(z[rf][3] + bb.w);
            }

            // ---- phase 2 half 1 (nt = 0..3) ----
            f32x4 acc[4];
            #pragma unroll
            for (int q = 0; q < 4; ++q) acc[q] = (f32x4)0.f;
            #pragma unroll
            for (int kk = 0; kk < 8; ++kk)
                #pragma unroll
                for (int q = 0; q < 4; ++q) {
                    half4_t bw = *(const half4_t*)&W2s[(((kk*8+q)*4+g)*16+ln)*4];
                    acc[q] = __builtin_amdgcn_mfma_f32_16x16x16f16(a2[kk], bw, acc[q], 0, 0, 0);
                }

            __syncthreads();   // B2: vmcnt(0) -> h DMA complete, hsh valid

            // ---- prefetch next chunk (covered by epilogue + phase2 half2) ----
            if (stage) {
                #pragma unroll
                for (int it = 0; it < 4; ++it) {
                    int r = nc + 4*w + 32*it + g;
                    jv[it] = (r < E) ? idx_j[r] : 0;
                }
                int e = nc + 16*w + ln;
                fA = make_float4(0.f,0.f,0.f,0.f);
                fB = make_float4(0.f,0.f,0.f,0.f);
                if (e < E) {
                    fA = *(const float4*)(f_ij + (size_t)e*20 + g*4);
                    if (g == 0) fB = *(const float4*)(f_ij + (size_t)e*20 + 16);
                }
            }
            asm volatile("" ::: "memory");   // pin prefetch issue point

            const bool same = (aiv[0] == aiv[3]);

            // ---- epilogue half 1 ----
            #pragma unroll
            for (int q = 0; q < 4; ++q) {
                const int pc = ((((q<<1) + lnhi) ^ g) << 3) + lnlo;  // swizzled col
                const float bb = b2v[q];
                if (same) {
                    float s = 0.f;
                    #pragma unroll
                    for (int r2 = 0; r2 < 4; ++r2)
                        s += (acc[q][r2] + bb) * rcv[r2] * (float)hsh[(brow+r2)*128 + pc];
                    atomicAdd(&bins[aiv[0]][q*16 + ln], s);
                } else {
                    #pragma unroll
                    for (int r2 = 0; r2 < 4; ++r2)
                        atomicAdd(&bins[aiv[r2]][q*16 + ln],
                                  (acc[q][r2] + bb) * rcv[r2] * (float)hsh[(brow+r2)*128 + pc]);
                }
            }

            // ---- phase 2 half 2 (nt = 4..7) ----
            #pragma unroll
            for (int q = 0; q < 4; ++q) acc[q] = (f32x4)0.f;
            #pragma unroll
            for (int kk = 0; kk < 8; ++kk)
                #pragma unroll
                for (int q = 0; q < 4; ++q) {
                    int nt = 4 + q;
                    half4_t bw = *(const half4_t*)&W2s[(((kk*8+nt)*4+g)*16+ln)*4];
                    acc[q] = __builtin_amdgcn_mfma_f32_16x16x16f16(a2[kk], bw, acc[q], 0, 0, 0);
                }
            // ---- epilogue half 2 ----
            #pragma unroll
            for (int q = 0; q < 4; ++q) {
                const int nt = 4 + q;
                const int pc = ((((nt<<1) + lnhi) ^ g) << 3) + lnlo;
                const float bb = b2v[nt];
                if (same) {
                    float s = 0.f;
                    #pragma unroll
                    for (int r2 = 0; r2 < 4; ++r2)
                        s += (acc[q][r2] + bb) * rcv[r2] * (float)hsh[(brow+r2)*128 + pc];
                    atomicAdd(&bins[aiv[0]][nt*16 + ln], s);
                } else {
                    #pragma unroll
                    for (int r2 = 0; r2 < 4; ++r2)
                        atomicAdd(&bins[aiv[r2]][nt*16 + ln],
                                  (acc[q][r2] + bb) * rcv[r2] * (float)hsh[(brow+r2)*128 + pc]);
                }
            }

            cur = chi;
        }
        // ---- group writeout + bins re-zero (one float4 per thread) ----
        __syncthreads();
        {
            int at = tid >> 5, c4 = tid & 31;
            int arow = a0 + at;
            float4 v = *(float4*)&bins[at][c4*4];
            if (arow < N) *(float4*)(agg + (size_t)arow*128 + c4*4) = v;
            *(float4*)&bins[at][c4*4] = make_float4(0.f,0.f,0.f,0.f);
        }
        // next adds happen only after next chunk's B1+B2 -> zeros visible
    }
}

extern "C" void kernel_launch(void* const* d_in, const int* in_sizes, int n_in,
                              void* d_out, int out_size, void* d_ws, size_t ws_size,
                              hipStream_t stream)
{
    const float* x      = (const float*)d_in[0];
    const float* f_ij   = (const float*)d_in[1];
    const float* rcut   = (const float*)d_in[2];
    const int*   idx_i  = (const int*)d_in[3];
    const int*   idx_j  = (const int*)d_in[4];
    const float* W_in2f = (const float*)d_in[5];
    const float* W_f1   = (const float*)d_in[6];
    const float* b_f1   = (const float*)d_in[7];
    const float* W_f2   = (const float*)d_in[8];
    const float* b_f2   = (const float*)d_in[9];
    const float* W_o1   = (const float*)d_in[10];
    const float* b_o1   = (const float*)d_in[11];
    const float* W_o2   = (const float*)d_in[12];
    const float* b_o2   = (const float*)d_in[13];

    const int N = in_sizes[0] / 128;
    const int E = in_sizes[2];

    // ws layout: h as f16 (aliases later t-f32 buffer), then weights
    half_t* h16  = (half_t*)d_ws;                       // [N,128] f16
    float*  tbuf = (float*)d_ws;                        // [N,128] f32 (after edge)
    half_t* wt   = (half_t*)((char*)d_ws + (size_t)N * 128 * 4);
    half_t* Wt_in2f = wt;                 // 16384 halfs
    half_t* Wt_f1   = wt + 16384;         //  4096 (layout compat)
    half_t* W2L     = wt + 16384 + 4096;  // 16384 (lane-linear W_f2)
    half_t* Wt_o1   = W2L + 16384;        // 16384
    half_t* Wt_o2   = Wt_o1 + 16384;      // 16384
    int* atom_start = (int*)(Wt_o2 + 16384);            // N+1 ints

    prep_weights<<<272, 256, 0, stream>>>(W_in2f, W_f1, W_f2, W_o1, W_o2,
                                          Wt_in2f, Wt_f1, W2L, Wt_o1, Wt_o2);
    seg_starts<<<(E + 255) / 256, 256, 0, stream>>>(idx_i, atom_start, E, N);

    const int gn  = (N + 63) / 64;
    const int nsg = (N + ATG - 1) / ATG;
    const int gpb = (nsg + 447) / 448;         // target <=448 blocks (2/CU, 1 round)
    const int nbl = (nsg + gpb - 1) / gpb;

    // h = x @ W_in2f  -> f16
    mfma_gemm<<<gn, 256, 0, stream>>>(x, Wt_in2f, nullptr, nullptr, h16, N, 2);

    // fused edge pipeline -> agg rows (full overwrite of d_out)
    edge_kernel<<<nbl, 512, 0, stream>>>(f_ij, rcut, idx_i, idx_j,
                                         W_f1, b_f1, W2L, b_f2,
                                         h16, (float*)d_out, atom_start, E, N, gpb);

    // t = ssp(agg @ W_o1 + b_o1)
    mfma_gemm<<<gn, 256, 0, stream>>>((const float*)d_out, Wt_o1, b_o1, tbuf, nullptr, N, 1);

    // out = t @ W_o2 + b_o2
    mfma_gemm<<<gn, 256, 0, stream>>>(tbuf, Wt_o2, b_o2, (float*)d_out, nullptr, N, 0);
}

// Round 8
// 408.803 us; speedup vs baseline: 2.4211x; 1.8829x over previous
//
#include <hip/hip_runtime.h>
#include <math.h>

#define LN2F 0.6931471805599453f

typedef _Float16 half_t;
typedef _Float16 half4_t __attribute__((ext_vector_type(4)));
typedef float f32x4 __attribute__((ext_vector_type(4)));

__device__ __forceinline__ float sspf(float z) {
    return fmaxf(z, 0.f) + __logf(1.f + __expf(-fabsf(z))) - LN2F;
}
__device__ __forceinline__ half4_t cvt4(float x, float y, float z, float w) {
    half4_t r; r[0]=(half_t)x; r[1]=(half_t)y; r[2]=(half_t)z; r[3]=(half_t)w; return r;
}

// async global->LDS DMA, 16 B per lane; dest = wave-uniform base + lane*16
__device__ __forceinline__ void load_lds16(const void* g, void* l) {
    __builtin_amdgcn_global_load_lds(
        (const __attribute__((address_space(1))) unsigned int*)g,
        (__attribute__((address_space(3))) unsigned int*)l, 16, 0, 0);
}

__device__ __forceinline__ int lbound(const int* __restrict__ a, int n, int key) {
    int lo = 0, hi = n;
    while (lo < hi) { int m = (lo + hi) >> 1; if (a[m] < key) lo = m + 1; else hi = m; }
    return lo;
}

// Weight prep (one launch) — identical layouts to R7 (validated)
__global__ __launch_bounds__(256) void prep_weights(
    const float* __restrict__ W_in2f, const float* __restrict__ W_f1,
    const float* __restrict__ W_f2, const float* __restrict__ W_o1,
    const float* __restrict__ W_o2,
    half_t* __restrict__ Wt_in2f, half_t* __restrict__ Wt_f1,
    half_t* __restrict__ W2L, half_t* __restrict__ Wt_o1,
    half_t* __restrict__ Wt_o2)
{
    int b = blockIdx.x;
    if (b < 64) {
        int i = b*256 + threadIdx.x;
        Wt_in2f[i] = (half_t)W_in2f[(i & 127)*128 + (i >> 7)];
    } else if (b < 80) {
        int i = (b-64)*256 + threadIdx.x;
        int n = i >> 5, k = i & 31;
        Wt_f1[i] = (k < 20) ? (half_t)W_f1[k*128 + n] : (half_t)0.f;
    } else if (b < 144) {
        int hidx = (b-80)*256 + threadIdx.x;
        int j = hidx & 3, i4 = hidx >> 2;
        int ln = i4 & 15, g = (i4 >> 4) & 3, nt = (i4 >> 6) & 7, kk = i4 >> 9;
        W2L[hidx] = (half_t)W_f2[(kk*16 + g*4 + j)*128 + nt*16 + ln];
    } else if (b < 208) {
        int i = (b-144)*256 + threadIdx.x;
        Wt_o1[i] = (half_t)W_o1[(i & 127)*128 + (i >> 7)];
    } else {
        int i = (b-208)*256 + threadIdx.x;
        Wt_o2[i] = (half_t)W_o2[(i & 127)*128 + (i >> 7)];
    }
}

// atom_start[a] = first edge index with idx_i >= a; atom_start[N] = E
__global__ __launch_bounds__(256) void seg_starts(
    const int* __restrict__ idx_i, int* __restrict__ atom_start, int E, int N)
{
    int e = blockIdx.x * 256 + threadIdx.x;
    if (e >= E) return;
    int a = idx_i[e];
    int prev = (e == 0) ? -1 : idx_i[e - 1];
    for (int k = prev + 1; k <= a; ++k) atom_start[k] = e;
    if (e == E - 1)
        for (int k = a + 1; k <= N; ++k) atom_start[k] = E;
}

// C = act(A @ B + bias); mode: 0 = f32, 1 = f32+ssp, 2 = f16 out
__global__ __launch_bounds__(256) void mfma_gemm(
    const float* __restrict__ A, const half_t* __restrict__ Bt,
    const float* __restrict__ bias, float* __restrict__ C,
    half_t* __restrict__ Ch, int nrows, int mode)
{
    const int tid = threadIdx.x;
    const int w = tid >> 6, l = tid & 63, g = l >> 4, ln = l & 15;
    const int r0 = blockIdx.x * 64;

    f32x4 acc[4][2];
    #pragma unroll
    for (int rf = 0; rf < 4; ++rf)
        #pragma unroll
        for (int cf = 0; cf < 2; ++cf) acc[rf][cf] = (f32x4)0.f;

    #pragma unroll
    for (int kk = 0; kk < 8; ++kk) {
        const int kb = kk * 16 + g * 4;
        half4_t a[4];
        #pragma unroll
        for (int rf = 0; rf < 4; ++rf) {
            int r = r0 + rf * 16 + ln;
            int rr = r < nrows ? r : nrows - 1;
            float4 av = *(const float4*)(A + (size_t)rr * 128 + kb);
            a[rf] = cvt4(av.x, av.y, av.z, av.w);
        }
        #pragma unroll
        for (int cf = 0; cf < 2; ++cf) {
            int n = w * 32 + cf * 16 + ln;
            half4_t b = *(const half4_t*)(Bt + (size_t)n * 128 + kb);
            #pragma unroll
            for (int rf = 0; rf < 4; ++rf)
                acc[rf][cf] = __builtin_amdgcn_mfma_f32_16x16x16f16(a[rf], b, acc[rf][cf], 0, 0, 0);
        }
    }

    #pragma unroll
    for (int cf = 0; cf < 2; ++cf) {
        int n = w * 32 + cf * 16 + ln;
        float bv = bias ? bias[n] : 0.f;
        #pragma unroll
        for (int rf = 0; rf < 4; ++rf) {
            #pragma unroll
            for (int reg = 0; reg < 4; ++reg) {
                int r = r0 + rf * 16 + g * 4 + reg;
                if (r < nrows) {
                    float v = acc[rf][cf][reg] + bv;
                    if (mode == 2)      Ch[(size_t)r * 128 + n] = (half_t)v;
                    else if (mode == 1) C[(size_t)r * 128 + n] = sspf(v);
                    else                C[(size_t)r * 128 + n] = v;
                }
            }
        }
    }
}

// Wave-independent fused edge pipeline. Each wave owns an atom range and
// streams 16-edge atom-aligned chunks with a private software pipeline:
//   DMA h(cur) -> prefetch next-chunk regs -> phase1+ssp(in-reg) ->
//   phase2 h1 -> s_waitcnt vmcnt(7) -> epilogue h1 -> phase2 h2 -> epilogue h2
// Per-atom accumulation in registers; shfl_xor reduce; one store per atom.
// NO __syncthreads in the main loop (vmcnt is per-wave).
__global__ __launch_bounds__(512, 4) void edge_kernel(
    const float* __restrict__ f_ij, const float* __restrict__ rcut,
    const int* __restrict__ idx_j,
    const float* __restrict__ W_f1, const float* __restrict__ b_f1,
    const half_t* __restrict__ W2L, const float* __restrict__ b_f2,
    const half_t* __restrict__ hh, float* __restrict__ agg,
    const int* __restrict__ atom_start, int E, int N, int W)
{
    __shared__ __align__(16) half_t W2s[16384];     // 32768 B
    __shared__ __align__(16) half_t hsh[8][2048];   // 32768 B (4KB per wave)
    __shared__ __align__(16) half_t W1s[128][24];   //  6144 B
    __shared__ float b1s[128];                      //   512 B
    __shared__ float b2s[128];                      //   512 B
    // 72704 B -> 2 blocks/CU

    const int tid = threadIdx.x;
    const int w = tid >> 6, l = tid & 63, g = l >> 4, ln = l & 15;
    const int lnh = ln >> 3, lnlo = ln & 7;

    // one-time staging
    for (int i = tid; i < 2048; i += 512)
        ((float4*)W2s)[i] = ((const float4*)W2L)[i];
    for (int i = tid; i < 128*24; i += 512) {
        int f = i / 24, k = i - f*24;
        W1s[f][k] = (k < 20) ? (half_t)W_f1[k*128 + f] : (half_t)0.f;
    }
    if (tid < 128) { b1s[tid] = b_f1[tid]; }
    else if (tid < 256) { int c = tid - 128; b2s[c] = b_f2[c]; }
    __syncthreads();

    // ---- per-wave atom range (edge-balanced) ----
    const int kg = blockIdx.x * 8 + w;
    const int aLo = lbound(atom_start, N + 1, (int)((size_t)kg * E / W));
    const int aHi = (kg == W - 1) ? N
                  : lbound(atom_start, N + 1, (int)((size_t)(kg + 1) * E / W));
    if (aLo >= aHi) return;

    half_t* const myhsh = &hsh[w][0];

    float b2v[8];
    #pragma unroll
    for (int q = 0; q < 8; ++q) b2v[q] = b2s[q*16 + ln];

    // ---- prologue: prefetch first chunk ----
    int cs = atom_start[aLo];
    int jvc[4]; float4 fAc = make_float4(0,0,0,0), fBc = make_float4(0,0,0,0);
    float rcc[4];
    {
        #pragma unroll
        for (int it = 0; it < 4; ++it) {
            int e = cs + 4*it + g;
            jvc[it] = (e < E) ? idx_j[e] : 0;
        }
        int e = cs + ln;
        if (e < E) {
            fAc = *(const float4*)(f_ij + (size_t)e*20 + g*4);
            if (g == 0) fBc = *(const float4*)(f_ij + (size_t)e*20 + 16);
        }
        #pragma unroll
        for (int r2 = 0; r2 < 4; ++r2) {
            int e2 = cs + 4*g + r2;
            rcc[r2] = (e2 < E) ? rcut[e2] : 0.f;
        }
    }
    asm volatile("" ::: "memory");

    for (int a = aLo; a < aHi; ++a) {
        const int ae = atom_start[a + 1];
        float racc[8];
        #pragma unroll
        for (int q = 0; q < 8; ++q) racc[q] = 0.f;

        while (cs < ae) {
            const int ce = min(cs + 16, ae);
            const int ncs = ce;               // next chunk start (atom-aligned stream)

            // ---- h DMA for current chunk (per-wave dest, seg^2it swizzle) ----
            #pragma unroll
            for (int it = 0; it < 4; ++it)
                load_lds16(hh + (size_t)jvc[it]*128 + ((ln ^ (2*it)) << 3),
                           myhsh + it*512);
            asm volatile("" ::: "memory");

            // ---- prefetch next chunk (>=7 vmem insts, after the DMAs) ----
            int jvn[4]; float4 fAn = make_float4(0,0,0,0), fBn = make_float4(0,0,0,0);
            float rcn[4];
            #pragma unroll
            for (int it = 0; it < 4; ++it) {
                int e = ncs + 4*it + g;
                jvn[it] = (e < E) ? idx_j[e] : 0;
            }
            {
                int e = ncs + ln;
                if (e < E) {
                    fAn = *(const float4*)(f_ij + (size_t)e*20 + g*4);
                    if (g == 0) fBn = *(const float4*)(f_ij + (size_t)e*20 + 16);
                }
            }
            #pragma unroll
            for (int r2 = 0; r2 < 4; ++r2) {
                int e2 = ncs + 4*g + r2;
                rcn[r2] = (e2 < E) ? rcut[e2] : 0.f;
            }
            asm volatile("" ::: "memory");

            // ---- phase 1 + ssp, per-rf fused (low z liveness) ----
            half4_t bfr0 = cvt4(fAc.x, fAc.y, fAc.z, fAc.w);
            half4_t bfr1;
            if (g == 0) bfr1 = cvt4(fBc.x, fBc.y, fBc.z, fBc.w);
            else { half4_t zz = {}; bfr1 = zz; }
            half4_t a2[8];
            #pragma unroll
            for (int rf = 0; rf < 8; ++rf) {
                f32x4 z = (f32x4)0.f;
                half4_t a0f = *(const half4_t*)&W1s[rf*16 + ln][g*4];
                z = __builtin_amdgcn_mfma_f32_16x16x16f16(a0f, bfr0, z, 0, 0, 0);
                half4_t a1f;
                if (g == 0) a1f = *(const half4_t*)&W1s[rf*16 + ln][16];
                else { half4_t zz = {}; a1f = zz; }
                z = __builtin_amdgcn_mfma_f32_16x16x16f16(a1f, bfr1, z, 0, 0, 0);
                float4 bb = *(const float4*)&b1s[rf*16 + g*4];
                a2[rf][0] = (half_t)sspf(z[0] + bb.x);
                a2[rf][1] = (half_t)sspf(z[1] + bb.y);
                a2[rf][2] = (half_t)sspf(z[2] + bb.z);
                a2[rf][3] = (half_t)sspf(z[3] + bb.w);
            }

            // rc mask for pad lanes (edges >= ce contribute 0)
            float rcm[4];
            #pragma unroll
            for (int r2 = 0; r2 < 4; ++r2)
                rcm[r2] = (cs + 4*g + r2 < ce) ? rcc[r2] : 0.f;

            // ---- phase 2 half 1 (nt = 0..3) ----
            f32x4 acc[4];
            #pragma unroll
            for (int q = 0; q < 4; ++q) acc[q] = (f32x4)0.f;
            #pragma unroll
            for (int kk = 0; kk < 8; ++kk)
                #pragma unroll
                for (int q = 0; q < 4; ++q) {
                    half4_t bw = *(const half4_t*)&W2s[(((kk*8+q)*4+g)*16+ln)*4];
                    acc[q] = __builtin_amdgcn_mfma_f32_16x16x16f16(a2[kk], bw, acc[q], 0, 0, 0);
                }

            // ---- wait: h DMA done (4 oldest); <=7 younger prefetch loads OK ----
            asm volatile("s_waitcnt vmcnt(7)" ::: "memory");
            __builtin_amdgcn_sched_barrier(0);

            // ---- epilogue half 1 -> racc ----
            #pragma unroll
            for (int q = 0; q < 4; ++q) {
                float s = 0.f;
                #pragma unroll
                for (int r2 = 0; r2 < 4; ++r2) {
                    int row = 4*g + r2;
                    int segp = (2*q + lnh) ^ (2*g);
                    float hv = (float)myhsh[row*128 + segp*8 + lnlo];
                    s += (acc[q][r2] + b2v[q]) * rcm[r2] * hv;
                }
                racc[q] += s;
            }

            // ---- phase 2 half 2 (nt = 4..7) ----
            #pragma unroll
            for (int q = 0; q < 4; ++q) acc[q] = (f32x4)0.f;
            #pragma unroll
            for (int kk = 0; kk < 8; ++kk)
                #pragma unroll
                for (int q = 0; q < 4; ++q) {
                    int nt = 4 + q;
                    half4_t bw = *(const half4_t*)&W2s[(((kk*8+nt)*4+g)*16+ln)*4];
                    acc[q] = __builtin_amdgcn_mfma_f32_16x16x16f16(a2[kk], bw, acc[q], 0, 0, 0);
                }
            // ---- epilogue half 2 -> racc ----
            #pragma unroll
            for (int q = 0; q < 4; ++q) {
                int nt = 4 + q;
                float s = 0.f;
                #pragma unroll
                for (int r2 = 0; r2 < 4; ++r2) {
                    int row = 4*g + r2;
                    int segp = (2*nt + lnh) ^ (2*g);
                    float hv = (float)myhsh[row*128 + segp*8 + lnlo];
                    s += (acc[q][r2] + b2v[nt]) * rcm[r2] * hv;
                }
                racc[nt] += s;
            }

            // rotate prefetch state
            #pragma unroll
            for (int it = 0; it < 4; ++it) jvc[it] = jvn[it];
            fAc = fAn; fBc = fBn;
            #pragma unroll
            for (int r2 = 0; r2 < 4; ++r2) rcc[r2] = rcn[r2];
            cs = ce;
        }

        // ---- atom done: reduce across g-groups, store row once ----
        #pragma unroll
        for (int q = 0; q < 8; ++q) {
            float r = racc[q];
            r += __shfl_xor(r, 16, 64);
            r += __shfl_xor(r, 32, 64);
            racc[q] = r;
        }
        if (g == 0) {
            #pragma unroll
            for (int q = 0; q < 8; ++q)
                agg[(size_t)a*128 + q*16 + ln] = racc[q];
        }
    }
}

extern "C" void kernel_launch(void* const* d_in, const int* in_sizes, int n_in,
                              void* d_out, int out_size, void* d_ws, size_t ws_size,
                              hipStream_t stream)
{
    const float* x      = (const float*)d_in[0];
    const float* f_ij   = (const float*)d_in[1];
    const float* rcut   = (const float*)d_in[2];
    const int*   idx_i  = (const int*)d_in[3];
    const int*   idx_j  = (const int*)d_in[4];
    const float* W_in2f = (const float*)d_in[5];
    const float* W_f1   = (const float*)d_in[6];
    const float* b_f1   = (const float*)d_in[7];
    const float* W_f2   = (const float*)d_in[8];
    const float* b_f2   = (const float*)d_in[9];
    const float* W_o1   = (const float*)d_in[10];
    const float* b_o1   = (const float*)d_in[11];
    const float* W_o2   = (const float*)d_in[12];
    const float* b_o2   = (const float*)d_in[13];

    const int N = in_sizes[0] / 128;
    const int E = in_sizes[2];

    half_t* h16  = (half_t*)d_ws;                       // [N,128] f16
    float*  tbuf = (float*)d_ws;                        // [N,128] f32 (after edge)
    half_t* wt   = (half_t*)((char*)d_ws + (size_t)N * 128 * 4);
    half_t* Wt_in2f = wt;                 // 16384 halfs
    half_t* Wt_f1   = wt + 16384;         //  4096 (layout compat)
    half_t* W2L     = wt + 16384 + 4096;  // 16384 (lane-linear W_f2)
    half_t* Wt_o1   = W2L + 16384;        // 16384
    half_t* Wt_o2   = Wt_o1 + 16384;      // 16384
    int* atom_start = (int*)(Wt_o2 + 16384);            // N+1 ints

    prep_weights<<<272, 256, 0, stream>>>(W_in2f, W_f1, W_f2, W_o1, W_o2,
                                          Wt_in2f, Wt_f1, W2L, Wt_o1, Wt_o2);
    seg_starts<<<(E + 255) / 256, 256, 0, stream>>>(idx_i, atom_start, E, N);

    const int gn  = (N + 63) / 64;
    const int nbl = 480;                  // 3840 waves, 2 blocks/CU, single round
    const int W   = nbl * 8;

    // h = x @ W_in2f  -> f16
    mfma_gemm<<<gn, 256, 0, stream>>>(x, Wt_in2f, nullptr, nullptr, h16, N, 2);

    // wave-independent fused edge pipeline -> agg (full overwrite of d_out)
    edge_kernel<<<nbl, 512, 0, stream>>>(f_ij, rcut, idx_j,
                                         W_f1, b_f1, W2L, b_f2,
                                         h16, (float*)d_out, atom_start, E, N, W);

    // t = ssp(agg @ W_o1 + b_o1)
    mfma_gemm<<<gn, 256, 0, stream>>>((const float*)d_out, Wt_o1, b_o1, tbuf, nullptr, N, 1);

    // out = t @ W_o2 + b_o2
    mfma_gemm<<<gn, 256, 0, stream>>>(tbuf, Wt_o2, b_o2, (float*)d_out, nullptr, N, 0);
}

// Round 9
// 389.762 us; speedup vs baseline: 2.5394x; 1.0489x over previous
//
#include <hip/hip_runtime.h>
#include <math.h>

#define LN2F 0.6931471805599453f
#define LOG2EF 1.4426950408889634f

typedef _Float16 half_t;
typedef _Float16 half4_t __attribute__((ext_vector_type(4)));
typedef float f32x4 __attribute__((ext_vector_type(4)));

__device__ __forceinline__ float sspf(float z) {   // safe version (node MLP)
    return fmaxf(z, 0.f) + __logf(1.f + __expf(-fabsf(z))) - LN2F;
}
__device__ __forceinline__ half4_t cvt4(float x, float y, float z, float w) {
    half4_t r; r[0]=(half_t)x; r[1]=(half_t)y; r[2]=(half_t)z; r[3]=(half_t)w; return r;
}

// async global->LDS DMA, 16 B per lane; dest = wave-uniform base + lane*16
__device__ __forceinline__ void load_lds16(const void* g, void* l) {
    __builtin_amdgcn_global_load_lds(
        (const __attribute__((address_space(1))) unsigned int*)g,
        (__attribute__((address_space(3))) unsigned int*)l, 16, 0, 0);
}

__device__ __forceinline__ int lbound(const int* __restrict__ a, int n, int key) {
    int lo = 0, hi = n;
    while (lo < hi) { int m = (lo + hi) >> 1; if (a[m] < key) lo = m + 1; else hi = m; }
    return lo;
}

// Weight prep — layouts validated in R5-R8; block 272 adds b1sc = b_f1*log2e
__global__ __launch_bounds__(256) void prep_weights(
    const float* __restrict__ W_in2f, const float* __restrict__ W_f1,
    const float* __restrict__ W_f2, const float* __restrict__ W_o1,
    const float* __restrict__ W_o2, const float* __restrict__ b_f1,
    half_t* __restrict__ Wt_in2f, half_t* __restrict__ Wt_f1,
    half_t* __restrict__ W2L, half_t* __restrict__ Wt_o1,
    half_t* __restrict__ Wt_o2, float* __restrict__ b1sc)
{
    int b = blockIdx.x;
    if (b < 64) {
        int i = b*256 + threadIdx.x;
        Wt_in2f[i] = (half_t)W_in2f[(i & 127)*128 + (i >> 7)];
    } else if (b < 80) {
        int i = (b-64)*256 + threadIdx.x;
        int n = i >> 5, k = i & 31;
        Wt_f1[i] = (k < 20) ? (half_t)W_f1[k*128 + n] : (half_t)0.f;
    } else if (b < 144) {
        int hidx = (b-80)*256 + threadIdx.x;
        int j = hidx & 3, i4 = hidx >> 2;
        int ln = i4 & 15, g = (i4 >> 4) & 3, nt = (i4 >> 6) & 7, kk = i4 >> 9;
        W2L[hidx] = (half_t)W_f2[(kk*16 + g*4 + j)*128 + nt*16 + ln];
    } else if (b < 208) {
        int i = (b-144)*256 + threadIdx.x;
        Wt_o1[i] = (half_t)W_o1[(i & 127)*128 + (i >> 7)];
    } else if (b < 272) {
        int i = (b-208)*256 + threadIdx.x;
        Wt_o2[i] = (half_t)W_o2[(i & 127)*128 + (i >> 7)];
    } else {
        if (threadIdx.x < 128) b1sc[threadIdx.x] = b_f1[threadIdx.x] * LOG2EF;
    }
}

// atom_start[a] = first edge index with idx_i >= a; atom_start[N] = E
__global__ __launch_bounds__(256) void seg_starts(
    const int* __restrict__ idx_i, int* __restrict__ atom_start, int E, int N)
{
    int e = blockIdx.x * 256 + threadIdx.x;
    if (e >= E) return;
    int a = idx_i[e];
    int prev = (e == 0) ? -1 : idx_i[e - 1];
    for (int k = prev + 1; k <= a; ++k) atom_start[k] = e;
    if (e == E - 1)
        for (int k = a + 1; k <= N; ++k) atom_start[k] = E;
}

// C = act(A @ B + bias); mode: 0 = f32, 1 = f32+ssp, 2 = f16 out
__global__ __launch_bounds__(256) void mfma_gemm(
    const float* __restrict__ A, const half_t* __restrict__ Bt,
    const float* __restrict__ bias, float* __restrict__ C,
    half_t* __restrict__ Ch, int nrows, int mode)
{
    const int tid = threadIdx.x;
    const int w = tid >> 6, l = tid & 63, g = l >> 4, ln = l & 15;
    const int r0 = blockIdx.x * 64;

    f32x4 acc[4][2];
    #pragma unroll
    for (int rf = 0; rf < 4; ++rf)
        #pragma unroll
        for (int cf = 0; cf < 2; ++cf) acc[rf][cf] = (f32x4)0.f;

    #pragma unroll
    for (int kk = 0; kk < 8; ++kk) {
        const int kb = kk * 16 + g * 4;
        half4_t a[4];
        #pragma unroll
        for (int rf = 0; rf < 4; ++rf) {
            int r = r0 + rf * 16 + ln;
            int rr = r < nrows ? r : nrows - 1;
            float4 av = *(const float4*)(A + (size_t)rr * 128 + kb);
            a[rf] = cvt4(av.x, av.y, av.z, av.w);
        }
        #pragma unroll
        for (int cf = 0; cf < 2; ++cf) {
            int n = w * 32 + cf * 16 + ln;
            half4_t b = *(const half4_t*)(Bt + (size_t)n * 128 + kb);
            #pragma unroll
            for (int rf = 0; rf < 4; ++rf)
                acc[rf][cf] = __builtin_amdgcn_mfma_f32_16x16x16f16(a[rf], b, acc[rf][cf], 0, 0, 0);
        }
    }

    #pragma unroll
    for (int cf = 0; cf < 2; ++cf) {
        int n = w * 32 + cf * 16 + ln;
        float bv = bias ? bias[n] : 0.f;
        #pragma unroll
        for (int rf = 0; rf < 4; ++rf) {
            #pragma unroll
            for (int reg = 0; reg < 4; ++reg) {
                int r = r0 + rf * 16 + g * 4 + reg;
                if (r < nrows) {
                    float v = acc[rf][cf][reg] + bv;
                    if (mode == 2)      Ch[(size_t)r * 128 + n] = (half_t)v;
                    else if (mode == 1) C[(size_t)r * 128 + n] = sspf(v);
                    else                C[(size_t)r * 128 + n] = v;
                }
            }
        }
    }
}

// Wave-independent edge pipeline with double-buffered h-DMA and strict
// counted vmcnt discipline (T3/T4 at wave level). 4 waves/block.
__global__ __launch_bounds__(256, 2) void edge_kernel(
    const float* __restrict__ f_ij, const float* __restrict__ rcut,
    const int* __restrict__ idx_j,
    const float* __restrict__ W_f1, const float* __restrict__ b1sc,
    const half_t* __restrict__ W2L, const float* __restrict__ b_f2,
    const half_t* __restrict__ hh, float* __restrict__ agg,
    const int* __restrict__ atom_start, int E, int N, int W)
{
    __shared__ __align__(16) half_t W2s[16384];        // 32768 B
    __shared__ __align__(16) half_t hsh[4][2][2048];   // 32768 B (dbuf, 4KB/wave)
    __shared__ __align__(16) half_t W1s[128][24];      //  6144 B
    __shared__ float b1s[128];                         //   512 B
    __shared__ float b2s[128];                         //   512 B
    // 72704 B -> 2 blocks/CU

    const int tid = threadIdx.x;
    const int w = tid >> 6, l = tid & 63, g = l >> 4, ln = l & 15;
    const int lnh = ln >> 3, lnlo = ln & 7;

    for (int i = tid; i < 2048; i += 256)
        ((float4*)W2s)[i] = ((const float4*)W2L)[i];
    for (int i = tid; i < 128*24; i += 256) {
        int f = i / 24, k = i - f*24;
        W1s[f][k] = (k < 20) ? (half_t)W_f1[k*128 + f] : (half_t)0.f;
    }
    if (tid < 128) b1s[tid] = b1sc[tid];
    else if (tid < 256) b2s[tid-128] = b_f2[tid-128];
    __syncthreads();

    // per-wave atom range (edge-balanced)
    const int kg = blockIdx.x * 4 + w;
    const int aLo = lbound(atom_start, N + 1, (int)((size_t)kg * E / W));
    const int aHi = (kg == W - 1) ? N
                  : lbound(atom_start, N + 1, (int)((size_t)(kg + 1) * E / W));
    if (aLo >= aHi) return;

    float b2v[8];
    #pragma unroll
    for (int q = 0; q < 8; ++q) b2v[q] = b2s[q*16 + ln];

    // atom window + chunk bounds
    int acur = aLo;
    int ends0 = atom_start[acur + 1];
    int ends1 = atom_start[min(acur + 2, N)];
    int ends2 = atom_start[min(acur + 3, N)];
    int cs = atom_start[acur];
    int ce = min(cs + 16, ends0);
    {
        // chunk-1 bounds
    }
    bool fl0 = (ce == ends0);
    int csn = ce;
    int cen = min(csn + 16, fl0 ? ends1 : ends0);

    // prologue: chunk-0 jv -> DMA(0) -> chunk-0 regs + chunk-1 jv
    int jvN[4];
    {
        int jv0[4];
        #pragma unroll
        for (int it = 0; it < 4; ++it)
            jv0[it] = idx_j[min(cs + 4*it + g, E - 1)];
        asm volatile("" ::: "memory");
        #pragma unroll
        for (int it = 0; it < 4; ++it)
            load_lds16(hh + (size_t)jv0[it]*128 + ((ln ^ (2*it)) << 3),
                       &hsh[w][0][it*512]);
        asm volatile("" ::: "memory");
    }
    float4 fA, fB;
    {
        int e = min(cs + ln, E - 1);
        fA = *(const float4*)(f_ij + (size_t)e*20 + g*4);
        fB = *(const float4*)(f_ij + (size_t)e*20 + 16);
    }
    float rc[4];
    #pragma unroll
    for (int r2 = 0; r2 < 4; ++r2) rc[r2] = rcut[min(cs + 4*g + r2, E - 1)];
    #pragma unroll
    for (int it = 0; it < 4; ++it) jvN[it] = idx_j[min(csn + 4*it + g, E - 1)];
    asm volatile("" ::: "memory");

    float racc[8];
    #pragma unroll
    for (int q = 0; q < 8; ++q) racc[q] = 0.f;
    int p = 0;

    while (acur < aHi) {
        // ---- 1: DMA(k+1) into buf[p^1] (exactly 4 vmem between fences) ----
        asm volatile("" ::: "memory");
        #pragma unroll
        for (int it = 0; it < 4; ++it)
            load_lds16(hh + (size_t)jvN[it]*128 + ((ln ^ (2*it)) << 3),
                       &hsh[w][p^1][it*512]);
        // ---- 2: retire DMA(k) + ALL older loads; keep DMA(k+1) in flight ----
        asm volatile("s_waitcnt vmcnt(4)" ::: "memory");
        __builtin_amdgcn_sched_barrier(0);

        // ---- 3a: consume prefetched regs NOW (no compiler re-waits later) ----
        half4_t bfr0 = cvt4(fA.x, fA.y, fA.z, fA.w);
        half4_t bfr1;
        if (g == 0) bfr1 = cvt4(fB.x, fB.y, fB.z, fB.w);
        else { half4_t zz = {}; bfr1 = zz; }
        float rcm[4];
        #pragma unroll
        for (int r2 = 0; r2 < 4; ++r2)
            rcm[r2] = (cs + 4*g + r2 < ce) ? rc[r2] : 0.f;
        const bool flushF = (ce == ends0);
        const bool f1 = (cen == (flushF ? ends1 : ends0));
        const int cs2 = cen;
        const int endsel = flushF ? (f1 ? ends2 : ends1) : (f1 ? ends1 : ends0);
        const int ce2 = min(cs2 + 16, endsel);

        // ---- 3b: prefetch chunk k+1 regs / chunk k+2 jv / atom window ----
        int jv2[4];
        #pragma unroll
        for (int it = 0; it < 4; ++it)
            jv2[it] = idx_j[min(cs2 + 4*it + g, E - 1)];
        float4 fA1, fB1;
        {
            int e = min(csn + ln, E - 1);
            fA1 = *(const float4*)(f_ij + (size_t)e*20 + g*4);
            fB1 = *(const float4*)(f_ij + (size_t)e*20 + 16);
        }
        float rc1[4];
        #pragma unroll
        for (int r2 = 0; r2 < 4; ++r2) rc1[r2] = rcut[min(csn + 4*g + r2, E - 1)];
        const int aeL = atom_start[min(acur + 4, N)];
        asm volatile("" ::: "memory");

        // ---- 4: phase 1 + fast softplus (bias pre-scaled by log2e) ----
        half4_t a2[8];
        #pragma unroll
        for (int rf = 0; rf < 8; ++rf) {
            f32x4 z = (f32x4)0.f;
            half4_t a0f = *(const half4_t*)&W1s[rf*16 + ln][g*4];
            z = __builtin_amdgcn_mfma_f32_16x16x16f16(a0f, bfr0, z, 0, 0, 0);
            half4_t a1f;
            if (g == 0) a1f = *(const half4_t*)&W1s[rf*16 + ln][16];
            else { half4_t zz = {}; a1f = zz; }
            z = __builtin_amdgcn_mfma_f32_16x16x16f16(a1f, bfr1, z, 0, 0, 0);
            float4 bb = *(const float4*)&b1s[rf*16 + g*4];
            #pragma unroll
            for (int j = 0; j < 4; ++j) {
                float u = fmaf(j==0 ? z[0] : (j==1 ? z[1] : (j==2 ? z[2] : z[3])),
                               LOG2EF, j==0 ? bb.x : (j==1 ? bb.y : (j==2 ? bb.z : bb.w)));
                float S = fmaf(log2f(1.f + exp2f(u)), LN2F, -LN2F);
                a2[rf][j] = (half_t)S;
            }
        }

        // ---- 5: phase 2 half 1 (nt 0..3) ----
        f32x4 acc[4];
        #pragma unroll
        for (int q = 0; q < 4; ++q) acc[q] = (f32x4)0.f;
        __builtin_amdgcn_s_setprio(1);
        #pragma unroll
        for (int kk = 0; kk < 8; ++kk)
            #pragma unroll
            for (int q = 0; q < 4; ++q) {
                half4_t bw = *(const half4_t*)&W2s[(((kk*8+q)*4+g)*16+ln)*4];
                acc[q] = __builtin_amdgcn_mfma_f32_16x16x16f16(a2[kk], bw, acc[q], 0, 0, 0);
            }
        __builtin_amdgcn_s_setprio(0);

        // ---- 6: epilogue half 1 (reads buf[p]; DMA(k) retired at step 2) ----
        #pragma unroll
        for (int q = 0; q < 4; ++q) {
            float s = 0.f;
            #pragma unroll
            for (int r2 = 0; r2 < 4; ++r2) {
                int segp = (2*q + lnh) ^ (2*g);
                float hv = (float)hsh[w][p][(4*g + r2)*128 + segp*8 + lnlo];
                s += (acc[q][r2] + b2v[q]) * rcm[r2] * hv;
            }
            racc[q] += s;
        }

        // ---- 7: phase 2 half 2 + epilogue half 2 ----
        #pragma unroll
        for (int q = 0; q < 4; ++q) acc[q] = (f32x4)0.f;
        __builtin_amdgcn_s_setprio(1);
        #pragma unroll
        for (int kk = 0; kk < 8; ++kk)
            #pragma unroll
            for (int q = 0; q < 4; ++q) {
                int nt = 4 + q;
                half4_t bw = *(const half4_t*)&W2s[(((kk*8+nt)*4+g)*16+ln)*4];
                acc[q] = __builtin_amdgcn_mfma_f32_16x16x16f16(a2[kk], bw, acc[q], 0, 0, 0);
            }
        __builtin_amdgcn_s_setprio(0);
        #pragma unroll
        for (int q = 0; q < 4; ++q) {
            int nt = 4 + q;
            float s = 0.f;
            #pragma unroll
            for (int r2 = 0; r2 < 4; ++r2) {
                int segp = (2*nt + lnh) ^ (2*g);
                float hv = (float)hsh[w][p][(4*g + r2)*128 + segp*8 + lnlo];
                s += (acc[q][r2] + b2v[nt]) * rcm[r2] * hv;
            }
            racc[nt] += s;
        }

        // ---- 8: atom flush (register racc -> shfl reduce -> one store) ----
        if (flushF) {
            #pragma unroll
            for (int q = 0; q < 8; ++q) {
                float r = racc[q];
                r += __shfl_xor(r, 16, 64);
                r += __shfl_xor(r, 32, 64);
                racc[q] = r;
            }
            if (g == 0) {
                #pragma unroll
                for (int q = 0; q < 8; ++q)
                    agg[(size_t)acur*128 + q*16 + ln] = racc[q];
            }
            #pragma unroll
            for (int q = 0; q < 8; ++q) racc[q] = 0.f;
            ++acur;
            ends0 = ends1; ends1 = ends2; ends2 = aeL;
        }

        // ---- 9: rotate pipeline state ----
        cs = csn; ce = cen; csn = cs2; cen = ce2;
        #pragma unroll
        for (int it = 0; it < 4; ++it) jvN[it] = jv2[it];
        fA = fA1; fB = fB1;
        #pragma unroll
        for (int r2 = 0; r2 < 4; ++r2) rc[r2] = rc1[r2];
        p ^= 1;
    }
}

extern "C" void kernel_launch(void* const* d_in, const int* in_sizes, int n_in,
                              void* d_out, int out_size, void* d_ws, size_t ws_size,
                              hipStream_t stream)
{
    const float* x      = (const float*)d_in[0];
    const float* f_ij   = (const float*)d_in[1];
    const float* rcut   = (const float*)d_in[2];
    const int*   idx_i  = (const int*)d_in[3];
    const int*   idx_j  = (const int*)d_in[4];
    const float* W_in2f = (const float*)d_in[5];
    const float* W_f1   = (const float*)d_in[6];
    const float* b_f1   = (const float*)d_in[7];
    const float* W_f2   = (const float*)d_in[8];
    const float* b_f2   = (const float*)d_in[9];
    const float* W_o1   = (const float*)d_in[10];
    const float* b_o1   = (const float*)d_in[11];
    const float* W_o2   = (const float*)d_in[12];
    const float* b_o2   = (const float*)d_in[13];

    const int N = in_sizes[0] / 128;
    const int E = in_sizes[2];

    half_t* h16  = (half_t*)d_ws;                       // [N,128] f16
    float*  tbuf = (float*)d_ws;                        // [N,128] f32 (after edge)
    half_t* wt   = (half_t*)((char*)d_ws + (size_t)N * 128 * 4);
    half_t* Wt_in2f = wt;                 // 16384 halfs
    half_t* Wt_f1   = wt + 16384;         //  4096 (layout compat)
    half_t* W2L     = wt + 16384 + 4096;  // 16384 (lane-linear W_f2)
    half_t* Wt_o1   = W2L + 16384;        // 16384
    half_t* Wt_o2   = Wt_o1 + 16384;      // 16384
    float*  b1sc    = (float*)(Wt_o2 + 16384);          // 128 floats
    int* atom_start = (int*)(b1sc + 128);               // N+1 ints

    prep_weights<<<273, 256, 0, stream>>>(W_in2f, W_f1, W_f2, W_o1, W_o2, b_f1,
                                          Wt_in2f, Wt_f1, W2L, Wt_o1, Wt_o2, b1sc);
    seg_starts<<<(E + 255) / 256, 256, 0, stream>>>(idx_i, atom_start, E, N);

    const int gn  = (N + 63) / 64;
    const int nbl = 512;                  // 4 waves/block, 2 blocks/CU, all-resident
    const int W   = nbl * 4;

    // h = x @ W_in2f  -> f16
    mfma_gemm<<<gn, 256, 0, stream>>>(x, Wt_in2f, nullptr, nullptr, h16, N, 2);

    // wave-independent fused edge pipeline -> agg (writes every atom row once)
    edge_kernel<<<nbl, 256, 0, stream>>>(f_ij, rcut, idx_j,
                                         W_f1, b1sc, W2L, b_f2,
                                         h16, (float*)d_out, atom_start, E, N, W);

    // t = ssp(agg @ W_o1 + b_o1)
    mfma_gemm<<<gn, 256, 0, stream>>>((const float*)d_out, Wt_o1, b_o1, tbuf, nullptr, N, 1);

    // out = t @ W_o2 + b_o2
    mfma_gemm<<<gn, 256, 0, stream>>>(tbuf, Wt_o2, b_o2, (float*)d_out, nullptr, N, 0);
}

// Round 11
// 306.550 us; speedup vs baseline: 3.2287x; 1.2714x over previous
//
#include <hip/hip_runtime.h>
#include <math.h>

#define LN2F 0.6931471805599453f
#define LOG2EF 1.4426950408889634f

typedef _Float16 half_t;
typedef _Float16 half4_t __attribute__((ext_vector_type(4)));
typedef _Float16 half8_t __attribute__((ext_vector_type(8)));
typedef __fp16 fp16x2 __attribute__((ext_vector_type(2)));
typedef __fp16 fp16x4 __attribute__((ext_vector_type(4)));
typedef float f32x4 __attribute__((ext_vector_type(4)));

__device__ __forceinline__ float sspf(float z) {   // safe version (node MLP)
    return fmaxf(z, 0.f) + __logf(1.f + __expf(-fabsf(z))) - LN2F;
}
__device__ __forceinline__ half4_t cvt4(float x, float y, float z, float w) {
    half4_t r; r[0]=(half_t)x; r[1]=(half_t)y; r[2]=(half_t)z; r[3]=(half_t)w; return r;
}
// pack 4 floats to half4 via v_cvt_pkrtz_f16_f32 (2 instrs)
__device__ __forceinline__ half4_t pk4(float a, float b, float c, float d) {
    fp16x2 lo = __builtin_amdgcn_cvt_pkrtz(a, b);
    fp16x2 hi = __builtin_amdgcn_cvt_pkrtz(c, d);
    fp16x4 v = __builtin_shufflevector(lo, hi, 0, 1, 2, 3);
    return __builtin_bit_cast(half4_t, v);
}

// async global->LDS DMA, 16 B per lane; dest = wave-uniform base + lane*16
__device__ __forceinline__ void load_lds16(const void* g, void* l) {
    __builtin_amdgcn_global_load_lds(
        (const __attribute__((address_space(1))) unsigned int*)g,
        (__attribute__((address_space(3))) unsigned int*)l, 16, 0, 0);
}

__device__ __forceinline__ int lbound(const int* __restrict__ a, int n, int key) {
    int lo = 0, hi = n;
    while (lo < hi) { int m = (lo + hi) >> 1; if (a[m] < key) lo = m + 1; else hi = m; }
    return lo;
}

// Weight prep.
//  Wt_in2f/Wt_o1/Wt_o2: dst[n*128+k] = W[k][n]  (f16)
//  W2L (PAIRED layout for ds_read_b128, pre-scaled by ln2):
//    flat i: j=i&3, s=(i>>2)&1, ln=(i>>3)&15, g=(i>>7)&3, m=(i>>9)&3, kk=i>>11
//    W2L[i] = ln2 * W_f2[(kk*16+g*4+j)*128 + (2m+s)*16+ln]
//  b1sc = b_f1*log2e ; b2a = b_f2 - ln2*colsum(W_f2)
__global__ __launch_bounds__(256) void prep_weights(
    const float* __restrict__ W_in2f, const float* __restrict__ W_f2,
    const float* __restrict__ W_o1, const float* __restrict__ W_o2,
    const float* __restrict__ b_f1, const float* __restrict__ b_f2,
    half_t* __restrict__ Wt_in2f, half_t* __restrict__ W2L,
    half_t* __restrict__ Wt_o1, half_t* __restrict__ Wt_o2,
    float* __restrict__ b1sc, float* __restrict__ b2a)
{
    int b = blockIdx.x;
    if (b < 64) {
        int i = b*256 + threadIdx.x;
        Wt_in2f[i] = (half_t)W_in2f[(i & 127)*128 + (i >> 7)];
    } else if (b < 128) {
        int i = (b-64)*256 + threadIdx.x;
        int j = i & 3, s = (i >> 2) & 1, ln = (i >> 3) & 15;
        int g = (i >> 7) & 3, m = (i >> 9) & 3, kk = i >> 11;
        W2L[i] = (half_t)(LN2F * W_f2[(kk*16 + g*4 + j)*128 + (2*m+s)*16 + ln]);
    } else if (b < 192) {
        int i = (b-128)*256 + threadIdx.x;
        Wt_o1[i] = (half_t)W_o1[(i & 127)*128 + (i >> 7)];
    } else if (b < 256) {
        int i = (b-192)*256 + threadIdx.x;
        Wt_o2[i] = (half_t)W_o2[(i & 127)*128 + (i >> 7)];
    } else {
        int c = threadIdx.x;
        if (c < 128) {
            float s = 0.f;
            for (int k = 0; k < 128; ++k) s += W_f2[k*128 + c];
            b2a[c]  = b_f2[c] - LN2F * s;
            b1sc[c] = b_f1[c] * LOG2EF;
        }
    }
}

// atom_start[a] = first edge index with idx_i >= a; atom_start[N] = E
__global__ __launch_bounds__(256) void seg_starts(
    const int* __restrict__ idx_i, int* __restrict__ atom_start, int E, int N)
{
    int e = blockIdx.x * 256 + threadIdx.x;
    if (e >= E) return;
    int a = idx_i[e];
    int prev = (e == 0) ? -1 : idx_i[e - 1];
    for (int k = prev + 1; k <= a; ++k) atom_start[k] = e;
    if (e == E - 1)
        for (int k = a + 1; k <= N; ++k) atom_start[k] = E;
}

// h = x @ W_in2f -> f16
__global__ __launch_bounds__(256) void mfma_gemm_h(
    const float* __restrict__ A, const half_t* __restrict__ Bt,
    half_t* __restrict__ Ch, int nrows)
{
    const int tid = threadIdx.x;
    const int w = tid >> 6, l = tid & 63, g = l >> 4, ln = l & 15;
    const int r0 = blockIdx.x * 64;

    f32x4 acc[4][2];
    #pragma unroll
    for (int rf = 0; rf < 4; ++rf)
        #pragma unroll
        for (int cf = 0; cf < 2; ++cf) acc[rf][cf] = (f32x4)0.f;

    #pragma unroll
    for (int kk = 0; kk < 8; ++kk) {
        const int kb = kk * 16 + g * 4;
        half4_t a[4];
        #pragma unroll
        for (int rf = 0; rf < 4; ++rf) {
            int r = r0 + rf * 16 + ln;
            int rr = r < nrows ? r : nrows - 1;
            float4 av = *(const float4*)(A + (size_t)rr * 128 + kb);
            a[rf] = cvt4(av.x, av.y, av.z, av.w);
        }
        #pragma unroll
        for (int cf = 0; cf < 2; ++cf) {
            int n = w * 32 + cf * 16 + ln;
            half4_t b = *(const half4_t*)(Bt + (size_t)n * 128 + kb);
            #pragma unroll
            for (int rf = 0; rf < 4; ++rf)
                acc[rf][cf] = __builtin_amdgcn_mfma_f32_16x16x16f16(a[rf], b, acc[rf][cf], 0, 0, 0);
        }
    }
    #pragma unroll
    for (int cf = 0; cf < 2; ++cf) {
        int n = w * 32 + cf * 16 + ln;
        #pragma unroll
        for (int rf = 0; rf < 4; ++rf)
            #pragma unroll
            for (int reg = 0; reg < 4; ++reg) {
                int r = r0 + rf * 16 + g * 4 + reg;
                if (r < nrows) Ch[(size_t)r * 128 + n] = (half_t)acc[rf][cf][reg];
            }
    }
}

// fused out-MLP: out = ssp(agg@O1+b1)@O2+b2  (t staged in LDS f16)
__global__ __launch_bounds__(256) void mfma_gemm2(
    const float* __restrict__ A, const half_t* __restrict__ Bt1,
    const float* __restrict__ bias1, const half_t* __restrict__ Bt2,
    const float* __restrict__ bias2, float* __restrict__ out, int nrows)
{
    __shared__ half_t ts[64][136];
    const int tid = threadIdx.x;
    const int w = tid >> 6, l = tid & 63, g = l >> 4, ln = l & 15;
    const int r0 = blockIdx.x * 64;

    // layer 1
    f32x4 acc[4][2];
    #pragma unroll
    for (int rf = 0; rf < 4; ++rf)
        #pragma unroll
        for (int cf = 0; cf < 2; ++cf) acc[rf][cf] = (f32x4)0.f;
    #pragma unroll
    for (int kk = 0; kk < 8; ++kk) {
        const int kb = kk * 16 + g * 4;
        half4_t a[4];
        #pragma unroll
        for (int rf = 0; rf < 4; ++rf) {
            int r = r0 + rf * 16 + ln;
            int rr = r < nrows ? r : nrows - 1;
            float4 av = *(const float4*)(A + (size_t)rr * 128 + kb);
            a[rf] = cvt4(av.x, av.y, av.z, av.w);
        }
        #pragma unroll
        for (int cf = 0; cf < 2; ++cf) {
            int n = w * 32 + cf * 16 + ln;
            half4_t b = *(const half4_t*)(Bt1 + (size_t)n * 128 + kb);
            #pragma unroll
            for (int rf = 0; rf < 4; ++rf)
                acc[rf][cf] = __builtin_amdgcn_mfma_f32_16x16x16f16(a[rf], b, acc[rf][cf], 0, 0, 0);
        }
    }
    #pragma unroll
    for (int cf = 0; cf < 2; ++cf) {
        int n = w * 32 + cf * 16 + ln;
        float bv = bias1[n];
        #pragma unroll
        for (int rf = 0; rf < 4; ++rf)
            #pragma unroll
            for (int reg = 0; reg < 4; ++reg)
                ts[rf*16 + g*4 + reg][n] = (half_t)sspf(acc[rf][cf][reg] + bv);
    }
    __syncthreads();

    // layer 2
    f32x4 acc2[4][2];
    #pragma unroll
    for (int rf = 0; rf < 4; ++rf)
        #pragma unroll
        for (int cf = 0; cf < 2; ++cf) acc2[rf][cf] = (f32x4)0.f;
    #pragma unroll
    for (int kk = 0; kk < 8; ++kk) {
        const int kb = kk * 16 + g * 4;
        half4_t a[4];
        #pragma unroll
        for (int rf = 0; rf < 4; ++rf)
            a[rf] = *(const half4_t*)&ts[rf*16 + ln][kb];
        #pragma unroll
        for (int cf = 0; cf < 2; ++cf) {
            int n = w * 32 + cf * 16 + ln;
            half4_t b = *(const half4_t*)(Bt2 + (size_t)n * 128 + kb);
            #pragma unroll
            for (int rf = 0; rf < 4; ++rf)
                acc2[rf][cf] = __builtin_amdgcn_mfma_f32_16x16x16f16(a[rf], b, acc2[rf][cf], 0, 0, 0);
        }
    }
    #pragma unroll
    for (int cf = 0; cf < 2; ++cf) {
        int n = w * 32 + cf * 16 + ln;
        float bv = bias2[n];
        #pragma unroll
        for (int rf = 0; rf < 4; ++rf)
            #pragma unroll
            for (int reg = 0; reg < 4; ++reg) {
                int r = r0 + rf * 16 + g * 4 + reg;
                if (r < nrows) out[(size_t)r * 128 + n] = acc2[rf][cf][reg] + bv;
            }
    }
}

// Wave-independent edge pipeline, double-buffered h-DMA, counted vmcnt.
// R10: softplus tail folded into W2'/b2', pkrtz packing, b2-seeded acc,
// b128 W2 fragment reads.
__global__ __launch_bounds__(256, 2) void edge_kernel(
    const float* __restrict__ f_ij, const float* __restrict__ rcut,
    const int* __restrict__ idx_j,
    const float* __restrict__ W_f1, const float* __restrict__ b1sc,
    const half_t* __restrict__ W2L, const float* __restrict__ b2a,
    const half_t* __restrict__ hh, float* __restrict__ agg,
    const int* __restrict__ atom_start, int E, int N, int W)
{
    __shared__ __align__(16) half_t W2s[16384];        // 32768 B
    __shared__ __align__(16) half_t hsh[4][2][2048];   // 32768 B (dbuf, 4KB/wave)
    __shared__ __align__(16) half_t W1s[128][24];      //  6144 B
    __shared__ float b1s[128];                         //   512 B
    // 72192 B -> 2 blocks/CU

    const int tid = threadIdx.x;
    const int w = tid >> 6, l = tid & 63, g = l >> 4, ln = l & 15;
    const int lnh = ln >> 3, lnlo = ln & 7;

    for (int i = tid; i < 2048; i += 256)
        ((float4*)W2s)[i] = ((const float4*)W2L)[i];
    for (int i = tid; i < 128*24; i += 256) {
        int f = i / 24, k = i - f*24;
        W1s[f][k] = (k < 20) ? (half_t)W_f1[k*128 + f] : (half_t)0.f;
    }
    if (tid < 128) b1s[tid] = b1sc[tid];
    __syncthreads();

    // per-wave atom range (edge-balanced)
    const int kg = blockIdx.x * 4 + w;
    const int aLo = lbound(atom_start, N + 1, (int)((size_t)kg * E / W));
    const int aHi = (kg == W - 1) ? N
                  : lbound(atom_start, N + 1, (int)((size_t)(kg + 1) * E / W));
    if (aLo >= aHi) return;

    float b2v[8];
    #pragma unroll
    for (int q = 0; q < 8; ++q) b2v[q] = b2a[q*16 + ln];

    // atom window + chunk bounds
    int acur = aLo;
    int ends0 = atom_start[acur + 1];
    int ends1 = atom_start[min(acur + 2, N)];
    int ends2 = atom_start[min(acur + 3, N)];
    int cs = atom_start[acur];
    int ce = min(cs + 16, ends0);
    bool fl0 = (ce == ends0);
    int csn = ce;
    int cen = min(csn + 16, fl0 ? ends1 : ends0);

    // prologue: chunk-0 jv -> DMA(0) -> chunk-0 regs + chunk-1 jv
    int jvN[4];
    {
        int jv0[4];
        #pragma unroll
        for (int it = 0; it < 4; ++it)
            jv0[it] = idx_j[min(cs + 4*it + g, E - 1)];
        asm volatile("" ::: "memory");
        #pragma unroll
        for (int it = 0; it < 4; ++it)
            load_lds16(hh + (size_t)jv0[it]*128 + ((ln ^ (2*it)) << 3),
                       &hsh[w][0][it*512]);
        asm volatile("" ::: "memory");
    }
    float4 fA, fB;
    {
        int e = min(cs + ln, E - 1);
        fA = *(const float4*)(f_ij + (size_t)e*20 + g*4);
        fB = *(const float4*)(f_ij + (size_t)e*20 + 16);
    }
    float rc[4];
    #pragma unroll
    for (int r2 = 0; r2 < 4; ++r2) rc[r2] = rcut[min(cs + 4*g + r2, E - 1)];
    #pragma unroll
    for (int it = 0; it < 4; ++it) jvN[it] = idx_j[min(csn + 4*it + g, E - 1)];
    asm volatile("" ::: "memory");

    float racc[8];
    #pragma unroll
    for (int q = 0; q < 8; ++q) racc[q] = 0.f;
    int p = 0;

    while (acur < aHi) {
        // ---- 1: DMA(k+1) into buf[p^1] (exactly 4 vmem between fences) ----
        asm volatile("" ::: "memory");
        #pragma unroll
        for (int it = 0; it < 4; ++it)
            load_lds16(hh + (size_t)jvN[it]*128 + ((ln ^ (2*it)) << 3),
                       &hsh[w][p^1][it*512]);
        // ---- 2: retire DMA(k) + ALL older loads; keep DMA(k+1) in flight ----
        asm volatile("s_waitcnt vmcnt(4)" ::: "memory");
        __builtin_amdgcn_sched_barrier(0);

        // ---- 3a: consume prefetched regs NOW ----
        half4_t bfr0 = cvt4(fA.x, fA.y, fA.z, fA.w);
        half4_t bfr1;
        if (g == 0) bfr1 = cvt4(fB.x, fB.y, fB.z, fB.w);
        else { half4_t zz = {}; bfr1 = zz; }
        float rcm[4];
        #pragma unroll
        for (int r2 = 0; r2 < 4; ++r2)
            rcm[r2] = (cs + 4*g + r2 < ce) ? rc[r2] : 0.f;
        const bool flushF = (ce == ends0);
        const bool f1 = (cen == (flushF ? ends1 : ends0));
        const int cs2 = cen;
        const int endsel = flushF ? (f1 ? ends2 : ends1) : (f1 ? ends1 : ends0);
        const int ce2 = min(cs2 + 16, endsel);

        // ---- 3b: prefetch chunk k+1 regs / chunk k+2 jv / atom window ----
        int jv2[4];
        #pragma unroll
        for (int it = 0; it < 4; ++it)
            jv2[it] = idx_j[min(cs2 + 4*it + g, E - 1)];
        float4 fA1, fB1;
        {
            int e = min(csn + ln, E - 1);
            fA1 = *(const float4*)(f_ij + (size_t)e*20 + g*4);
            fB1 = *(const float4*)(f_ij + (size_t)e*20 + 16);
        }
        float rc1[4];
        #pragma unroll
        for (int r2 = 0; r2 < 4; ++r2) rc1[r2] = rcut[min(csn + 4*g + r2, E - 1)];
        const int aeL = atom_start[min(acur + 4, N)];
        asm volatile("" ::: "memory");

        // ---- 4: phase 1 + folded softplus: a2 = log2(1 + 2^u) ----
        half4_t a2[8];
        #pragma unroll
        for (int rf = 0; rf < 8; ++rf) {
            f32x4 z = (f32x4)0.f;
            half4_t a0f = *(const half4_t*)&W1s[rf*16 + ln][g*4];
            z = __builtin_amdgcn_mfma_f32_16x16x16f16(a0f, bfr0, z, 0, 0, 0);
            half4_t a1f;
            if (g == 0) a1f = *(const half4_t*)&W1s[rf*16 + ln][16];
            else { half4_t zz = {}; a1f = zz; }
            z = __builtin_amdgcn_mfma_f32_16x16x16f16(a1f, bfr1, z, 0, 0, 0);
            float4 bb = *(const float4*)&b1s[rf*16 + g*4];
            float l0 = __log2f(1.f + exp2f(fmaf(z[0], LOG2EF, bb.x)));
            float l1 = __log2f(1.f + exp2f(fmaf(z[1], LOG2EF, bb.y)));
            float l2 = __log2f(1.f + exp2f(fmaf(z[2], LOG2EF, bb.z)));
            float l3 = __log2f(1.f + exp2f(fmaf(z[3], LOG2EF, bb.w)));
            a2[rf] = pk4(l0, l1, l2, l3);
        }

        // ---- 5: phase 2 half 1 (nt 0..3), acc seeded with b2' ----
        f32x4 acc[4];
        #pragma unroll
        for (int q = 0; q < 4; ++q) { f32x4 t = {b2v[q], b2v[q], b2v[q], b2v[q]}; acc[q] = t; }
        __builtin_amdgcn_s_setprio(1);
        #pragma unroll
        for (int kk = 0; kk < 8; ++kk)
            #pragma unroll
            for (int m = 0; m < 2; ++m) {
                half8_t bw = *(const half8_t*)&W2s[(((kk*4 + m)*4 + g)*16 + ln)*8];
                half4_t blo = __builtin_shufflevector(bw, bw, 0, 1, 2, 3);
                half4_t bhi = __builtin_shufflevector(bw, bw, 4, 5, 6, 7);
                acc[2*m]   = __builtin_amdgcn_mfma_f32_16x16x16f16(a2[kk], blo, acc[2*m],   0, 0, 0);
                acc[2*m+1] = __builtin_amdgcn_mfma_f32_16x16x16f16(a2[kk], bhi, acc[2*m+1], 0, 0, 0);
            }
        __builtin_amdgcn_s_setprio(0);

        // ---- 6: epilogue half 1 ----
        #pragma unroll
        for (int q = 0; q < 4; ++q) {
            float s = 0.f;
            #pragma unroll
            for (int r2 = 0; r2 < 4; ++r2) {
                int segp = (2*q + lnh) ^ (2*g);
                float hv = (float)hsh[w][p][(4*g + r2)*128 + segp*8 + lnlo];
                s = fmaf(acc[q][r2] * rcm[r2], hv, s);
            }
            racc[q] += s;
        }

        // ---- 7: phase 2 half 2 (nt 4..7) + epilogue half 2 ----
        #pragma unroll
        for (int q = 0; q < 4; ++q) { f32x4 t = {b2v[4+q], b2v[4+q], b2v[4+q], b2v[4+q]}; acc[q] = t; }
        __builtin_amdgcn_s_setprio(1);
        #pragma unroll
        for (int kk = 0; kk < 8; ++kk)
            #pragma unroll
            for (int m = 2; m < 4; ++m) {
                half8_t bw = *(const half8_t*)&W2s[(((kk*4 + m)*4 + g)*16 + ln)*8];
                half4_t blo = __builtin_shufflevector(bw, bw, 0, 1, 2, 3);
                half4_t bhi = __builtin_shufflevector(bw, bw, 4, 5, 6, 7);
                acc[2*(m-2)]   = __builtin_amdgcn_mfma_f32_16x16x16f16(a2[kk], blo, acc[2*(m-2)],   0, 0, 0);
                acc[2*(m-2)+1] = __builtin_amdgcn_mfma_f32_16x16x16f16(a2[kk], bhi, acc[2*(m-2)+1], 0, 0, 0);
            }
        __builtin_amdgcn_s_setprio(0);
        #pragma unroll
        for (int q = 0; q < 4; ++q) {
            int nt = 4 + q;
            float s = 0.f;
            #pragma unroll
            for (int r2 = 0; r2 < 4; ++r2) {
                int segp = (2*nt + lnh) ^ (2*g);
                float hv = (float)hsh[w][p][(4*g + r2)*128 + segp*8 + lnlo];
                s = fmaf(acc[q][r2] * rcm[r2], hv, s);
            }
            racc[nt] += s;
        }

        // ---- 8: atom flush ----
        if (flushF) {
            #pragma unroll
            for (int q = 0; q < 8; ++q) {
                float r = racc[q];
                r += __shfl_xor(r, 16, 64);
                r += __shfl_xor(r, 32, 64);
                racc[q] = r;
            }
            if (g == 0) {
                #pragma unroll
                for (int q = 0; q < 8; ++q)
                    agg[(size_t)acur*128 + q*16 + ln] = racc[q];
            }
            #pragma unroll
            for (int q = 0; q < 8; ++q) racc[q] = 0.f;
            ++acur;
            ends0 = ends1; ends1 = ends2; ends2 = aeL;
        }

        // ---- 9: rotate pipeline state ----
        cs = csn; ce = cen; csn = cs2; cen = ce2;
        #pragma unroll
        for (int it = 0; it < 4; ++it) jvN[it] = jv2[it];
        fA = fA1; fB = fB1;
        #pragma unroll
        for (int r2 = 0; r2 < 4; ++r2) rc[r2] = rc1[r2];
        p ^= 1;
    }
}

extern "C" void kernel_launch(void* const* d_in, const int* in_sizes, int n_in,
                              void* d_out, int out_size, void* d_ws, size_t ws_size,
                              hipStream_t stream)
{
    const float* x      = (const float*)d_in[0];
    const float* f_ij   = (const float*)d_in[1];
    const float* rcut   = (const float*)d_in[2];
    const int*   idx_i  = (const int*)d_in[3];
    const int*   idx_j  = (const int*)d_in[4];
    const float* W_in2f = (const float*)d_in[5];
    const float* W_f1   = (const float*)d_in[6];
    const float* b_f1   = (const float*)d_in[7];
    const float* W_f2   = (const float*)d_in[8];
    const float* b_f2   = (const float*)d_in[9];
    const float* W_o1   = (const float*)d_in[10];
    const float* b_o1   = (const float*)d_in[11];
    const float* W_o2   = (const float*)d_in[12];
    const float* b_o2   = (const float*)d_in[13];

    const int N = in_sizes[0] / 128;
    const int E = in_sizes[2];

    half_t* h16  = (half_t*)d_ws;                       // [N,128] f16
    half_t* wt   = (half_t*)((char*)d_ws + (size_t)N * 128 * 4);
    half_t* Wt_in2f = wt;                 // 16384 halfs
    half_t* W2L     = wt + 16384;         // 16384 (paired lane-linear W_f2 * ln2)
    half_t* Wt_o1   = W2L + 16384;        // 16384
    half_t* Wt_o2   = Wt_o1 + 16384;      // 16384
    float*  b1sc    = (float*)(Wt_o2 + 16384);          // 128 floats
    float*  b2a     = b1sc + 128;                       // 128 floats
    int* atom_start = (int*)(b2a + 128);                // N+1 ints

    prep_weights<<<257, 256, 0, stream>>>(W_in2f, W_f2, W_o1, W_o2, b_f1, b_f2,
                                          Wt_in2f, W2L, Wt_o1, Wt_o2, b1sc, b2a);
    seg_starts<<<(E + 255) / 256, 256, 0, stream>>>(idx_i, atom_start, E, N);

    const int gn  = (N + 63) / 64;
    const int nbl = 512;                  // 4 waves/block, 2 blocks/CU
    const int W   = nbl * 4;

    // h = x @ W_in2f -> f16
    mfma_gemm_h<<<gn, 256, 0, stream>>>(x, Wt_in2f, h16, N);

    // wave-independent fused edge pipeline -> agg (writes every atom row once)
    edge_kernel<<<nbl, 256, 0, stream>>>(f_ij, rcut, idx_j,
                                         W_f1, b1sc, W2L, b2a,
                                         h16, (float*)d_out, atom_start, E, N, W);

    // out = ssp(agg @ W_o1 + b_o1) @ W_o2 + b_o2   (fused, in-place on d_out)
    mfma_gemm2<<<gn, 256, 0, stream>>>((const float*)d_out, Wt_o1, b_o1,
                                       Wt_o2, b_o2, (float*)d_out, N);
}

// Round 12
// 267.428 us; speedup vs baseline: 3.7010x; 1.1463x over previous
//
#include <hip/hip_runtime.h>
#include <math.h>

#define LN2F 0.6931471805599453f
#define LOG2EF 1.4426950408889634f

typedef _Float16 half_t;
typedef _Float16 half4_t __attribute__((ext_vector_type(4)));
typedef _Float16 half8_t __attribute__((ext_vector_type(8)));
typedef __fp16 fp16x2 __attribute__((ext_vector_type(2)));
typedef __fp16 fp16x4 __attribute__((ext_vector_type(4)));
typedef __fp16 fp16x8 __attribute__((ext_vector_type(8)));
typedef float f32x4 __attribute__((ext_vector_type(4)));

__device__ __forceinline__ float sspf(float z) {   // safe version (node MLP)
    return fmaxf(z, 0.f) + __logf(1.f + __expf(-fabsf(z))) - LN2F;
}
__device__ __forceinline__ half4_t cvt4(float x, float y, float z, float w) {
    half4_t r; r[0]=(half_t)x; r[1]=(half_t)y; r[2]=(half_t)z; r[3]=(half_t)w; return r;
}
// pack 8 floats to half8 via v_cvt_pkrtz_f16_f32 (4 instrs)
__device__ __forceinline__ half8_t pk8(float a, float b, float c, float d,
                                       float e, float f, float g, float h) {
    fp16x2 p0 = __builtin_amdgcn_cvt_pkrtz(a, b);
    fp16x2 p1 = __builtin_amdgcn_cvt_pkrtz(c, d);
    fp16x2 p2 = __builtin_amdgcn_cvt_pkrtz(e, f);
    fp16x2 p3 = __builtin_amdgcn_cvt_pkrtz(g, h);
    fp16x4 lo = __builtin_shufflevector(p0, p1, 0, 1, 2, 3);
    fp16x4 hi = __builtin_shufflevector(p2, p3, 0, 1, 2, 3);
    fp16x8 v  = __builtin_shufflevector(lo, hi, 0, 1, 2, 3, 4, 5, 6, 7);
    return __builtin_bit_cast(half8_t, v);
}

// async global->LDS DMA, 16 B per lane; dest = wave-uniform base + lane*16
__device__ __forceinline__ void load_lds16(const void* g, void* l) {
    __builtin_amdgcn_global_load_lds(
        (const __attribute__((address_space(1))) unsigned int*)g,
        (__attribute__((address_space(3))) unsigned int*)l, 16, 0, 0);
}

__device__ __forceinline__ int lbound(const int* __restrict__ a, int n, int key) {
    int lo = 0, hi = n;
    while (lo < hi) { int m = (lo + hi) >> 1; if (a[m] < key) lo = m + 1; else hi = m; }
    return lo;
}

// Weight prep.
//  Wt_in2f/Wt_o1/Wt_o2: dst[n*128+k] = W[k][n]  (f16)
//  Wt_f1: dst[n*32+k] = W_f1[k][n], k<20 else 0   (x32 A-frags, K-padded)
//  W2L (x32-stacked layout, pre-scaled by ln2):
//    flat i: j=i&7, ln=(i>>3)&15, g=(i>>7)&3, nt=(i>>9)&7, t=i>>12
//    k = 32t + (j<4 ? g*4+j : 16+g*4+(j-4))
//    W2L[i] = ln2 * W_f2[k*128 + nt*16+ln]
//  b1sc = b_f1*log2e ; b2a = b_f2 - ln2*colsum(W_f2)
__global__ __launch_bounds__(256) void prep_weights(
    const float* __restrict__ W_in2f, const float* __restrict__ W_f1,
    const float* __restrict__ W_f2, const float* __restrict__ W_o1,
    const float* __restrict__ W_o2,
    const float* __restrict__ b_f1, const float* __restrict__ b_f2,
    half_t* __restrict__ Wt_in2f, half_t* __restrict__ Wt_f1,
    half_t* __restrict__ W2L, half_t* __restrict__ Wt_o1,
    half_t* __restrict__ Wt_o2, float* __restrict__ b1sc, float* __restrict__ b2a)
{
    int b = blockIdx.x;
    if (b < 64) {
        int i = b*256 + threadIdx.x;
        Wt_in2f[i] = (half_t)W_in2f[(i & 127)*128 + (i >> 7)];
    } else if (b < 80) {
        int i = (b-64)*256 + threadIdx.x;
        int n = i >> 5, k = i & 31;
        Wt_f1[i] = (k < 20) ? (half_t)W_f1[k*128 + n] : (half_t)0.f;
    } else if (b < 144) {
        int i = (b-80)*256 + threadIdx.x;     // 0..16383
        int j = i & 7, ln = (i >> 3) & 15, g = (i >> 7) & 3;
        int nt = (i >> 9) & 7, t = i >> 12;
        int k = 32*t + ((j < 4) ? (g*4 + j) : (16 + g*4 + (j - 4)));
        W2L[i] = (half_t)(LN2F * W_f2[k*128 + nt*16 + ln]);
    } else if (b < 208) {
        int i = (b-144)*256 + threadIdx.x;
        Wt_o1[i] = (half_t)W_o1[(i & 127)*128 + (i >> 7)];
    } else if (b < 272) {
        int i = (b-208)*256 + threadIdx.x;
        Wt_o2[i] = (half_t)W_o2[(i & 127)*128 + (i >> 7)];
    } else {
        int c = threadIdx.x;
        if (c < 128) {
            float s = 0.f;
            for (int k = 0; k < 128; ++k) s += W_f2[k*128 + c];
            b2a[c]  = b_f2[c] - LN2F * s;
            b1sc[c] = b_f1[c] * LOG2EF;
        }
    }
}

// atom_start[a] = first edge index with idx_i >= a; atom_start[N] = E
__global__ __launch_bounds__(256) void seg_starts(
    const int* __restrict__ idx_i, int* __restrict__ atom_start, int E, int N)
{
    int e = blockIdx.x * 256 + threadIdx.x;
    if (e >= E) return;
    int a = idx_i[e];
    int prev = (e == 0) ? -1 : idx_i[e - 1];
    for (int k = prev + 1; k <= a; ++k) atom_start[k] = e;
    if (e == E - 1)
        for (int k = a + 1; k <= N; ++k) atom_start[k] = E;
}

// h = x @ W_in2f -> f16
__global__ __launch_bounds__(256) void mfma_gemm_h(
    const float* __restrict__ A, const half_t* __restrict__ Bt,
    half_t* __restrict__ Ch, int nrows)
{
    const int tid = threadIdx.x;
    const int w = tid >> 6, l = tid & 63, g = l >> 4, ln = l & 15;
    const int r0 = blockIdx.x * 64;

    f32x4 acc[4][2];
    #pragma unroll
    for (int rf = 0; rf < 4; ++rf)
        #pragma unroll
        for (int cf = 0; cf < 2; ++cf) acc[rf][cf] = (f32x4)0.f;

    #pragma unroll
    for (int kk = 0; kk < 8; ++kk) {
        const int kb = kk * 16 + g * 4;
        half4_t a[4];
        #pragma unroll
        for (int rf = 0; rf < 4; ++rf) {
            int r = r0 + rf * 16 + ln;
            int rr = r < nrows ? r : nrows - 1;
            float4 av = *(const float4*)(A + (size_t)rr * 128 + kb);
            a[rf] = cvt4(av.x, av.y, av.z, av.w);
        }
        #pragma unroll
        for (int cf = 0; cf < 2; ++cf) {
            int n = w * 32 + cf * 16 + ln;
            half4_t b = *(const half4_t*)(Bt + (size_t)n * 128 + kb);
            #pragma unroll
            for (int rf = 0; rf < 4; ++rf)
                acc[rf][cf] = __builtin_amdgcn_mfma_f32_16x16x16f16(a[rf], b, acc[rf][cf], 0, 0, 0);
        }
    }
    #pragma unroll
    for (int cf = 0; cf < 2; ++cf) {
        int n = w * 32 + cf * 16 + ln;
        #pragma unroll
        for (int rf = 0; rf < 4; ++rf)
            #pragma unroll
            for (int reg = 0; reg < 4; ++reg) {
                int r = r0 + rf * 16 + g * 4 + reg;
                if (r < nrows) Ch[(size_t)r * 128 + n] = (half_t)acc[rf][cf][reg];
            }
    }
}

// fused out-MLP: out = ssp(agg@O1+b1)@O2+b2  (t staged in LDS f16)
__global__ __launch_bounds__(256) void mfma_gemm2(
    const float* __restrict__ A, const half_t* __restrict__ Bt1,
    const float* __restrict__ bias1, const half_t* __restrict__ Bt2,
    const float* __restrict__ bias2, float* __restrict__ out, int nrows)
{
    __shared__ half_t ts[64][136];
    const int tid = threadIdx.x;
    const int w = tid >> 6, l = tid & 63, g = l >> 4, ln = l & 15;
    const int r0 = blockIdx.x * 64;

    // layer 1
    f32x4 acc[4][2];
    #pragma unroll
    for (int rf = 0; rf < 4; ++rf)
        #pragma unroll
        for (int cf = 0; cf < 2; ++cf) acc[rf][cf] = (f32x4)0.f;
    #pragma unroll
    for (int kk = 0; kk < 8; ++kk) {
        const int kb = kk * 16 + g * 4;
        half4_t a[4];
        #pragma unroll
        for (int rf = 0; rf < 4; ++rf) {
            int r = r0 + rf * 16 + ln;
            int rr = r < nrows ? r : nrows - 1;
            float4 av = *(const float4*)(A + (size_t)rr * 128 + kb);
            a[rf] = cvt4(av.x, av.y, av.z, av.w);
        }
        #pragma unroll
        for (int cf = 0; cf < 2; ++cf) {
            int n = w * 32 + cf * 16 + ln;
            half4_t b = *(const half4_t*)(Bt1 + (size_t)n * 128 + kb);
            #pragma unroll
            for (int rf = 0; rf < 4; ++rf)
                acc[rf][cf] = __builtin_amdgcn_mfma_f32_16x16x16f16(a[rf], b, acc[rf][cf], 0, 0, 0);
        }
    }
    #pragma unroll
    for (int cf = 0; cf < 2; ++cf) {
        int n = w * 32 + cf * 16 + ln;
        float bv = bias1[n];
        #pragma unroll
        for (int rf = 0; rf < 4; ++rf)
            #pragma unroll
            for (int reg = 0; reg < 4; ++reg)
                ts[rf*16 + g*4 + reg][n] = (half_t)sspf(acc[rf][cf][reg] + bv);
    }
    __syncthreads();

    // layer 2
    f32x4 acc2[4][2];
    #pragma unroll
    for (int rf = 0; rf < 4; ++rf)
        #pragma unroll
        for (int cf = 0; cf < 2; ++cf) acc2[rf][cf] = (f32x4)0.f;
    #pragma unroll
    for (int kk = 0; kk < 8; ++kk) {
        const int kb = kk * 16 + g * 4;
        half4_t a[4];
        #pragma unroll
        for (int rf = 0; rf < 4; ++rf)
            a[rf] = *(const half4_t*)&ts[rf*16 + ln][kb];
        #pragma unroll
        for (int cf = 0; cf < 2; ++cf) {
            int n = w * 32 + cf * 16 + ln;
            half4_t b = *(const half4_t*)(Bt2 + (size_t)n * 128 + kb);
            #pragma unroll
            for (int rf = 0; rf < 4; ++rf)
                acc2[rf][cf] = __builtin_amdgcn_mfma_f32_16x16x16f16(a[rf], b, acc2[rf][cf], 0, 0, 0);
        }
    }
    #pragma unroll
    for (int cf = 0; cf < 2; ++cf) {
        int n = w * 32 + cf * 16 + ln;
        float bv = bias2[n];
        #pragma unroll
        for (int rf = 0; rf < 4; ++rf)
            #pragma unroll
            for (int reg = 0; reg < 4; ++reg) {
                int r = r0 + rf * 16 + g * 4 + reg;
                if (r < nrows) out[(size_t)r * 128 + n] = acc2[rf][cf][reg] + bv;
            }
    }
}

// Wave-independent edge pipeline, double-buffered h-DMA, counted vmcnt.
// R12: 16x16x32 MFMA (stacked-K frags), W1 frags in VGPRs, 1:1 b128->MFMA.
__global__ __launch_bounds__(256, 2) void edge_kernel(
    const float* __restrict__ f_ij, const float* __restrict__ rcut,
    const int* __restrict__ idx_j,
    const half_t* __restrict__ Wt_f1, const float* __restrict__ b1sc,
    const half_t* __restrict__ W2L, const float* __restrict__ b2a,
    const half_t* __restrict__ hh, float* __restrict__ agg,
    const int* __restrict__ atom_start, int E, int N, int W)
{
    __shared__ __align__(16) half_t W2s[16384];        // 32768 B
    __shared__ __align__(16) half_t hsh[4][2][2048];   // 32768 B (dbuf, 4KB/wave)
    __shared__ float b1s[128];                         //   512 B
    // 66048 B -> 2 blocks/CU

    const int tid = threadIdx.x;
    const int w = tid >> 6, l = tid & 63, g = l >> 4, ln = l & 15;
    const int lnh = ln >> 3, lnlo = ln & 7;

    for (int i = tid; i < 2048; i += 256)
        ((float4*)W2s)[i] = ((const float4*)W2L)[i];
    if (tid < 128) b1s[tid] = b1sc[tid];
    __syncthreads();

    // per-wave atom range (edge-balanced)
    const int kg = blockIdx.x * 4 + w;
    const int aLo = lbound(atom_start, N + 1, (int)((size_t)kg * E / W));
    const int aHi = (kg == W - 1) ? N
                  : lbound(atom_start, N + 1, (int)((size_t)(kg + 1) * E / W));
    if (aLo >= aHi) return;

    // W1 A-frags in VGPRs (x32 stacked-K: lower=k g*4.., upper=k 16+g*4..)
    half8_t w1f[8];
    #pragma unroll
    for (int rf = 0; rf < 8; ++rf) {
        half4_t lo = *(const half4_t*)(Wt_f1 + (size_t)(rf*16 + ln)*32 + g*4);
        half4_t hi = *(const half4_t*)(Wt_f1 + (size_t)(rf*16 + ln)*32 + 16 + g*4);
        w1f[rf] = __builtin_shufflevector(lo, hi, 0, 1, 2, 3, 4, 5, 6, 7);
    }

    float b2v[8];
    #pragma unroll
    for (int q = 0; q < 8; ++q) b2v[q] = b2a[q*16 + ln];

    // atom window + chunk bounds
    int acur = aLo;
    int ends0 = atom_start[acur + 1];
    int ends1 = atom_start[min(acur + 2, N)];
    int ends2 = atom_start[min(acur + 3, N)];
    int cs = atom_start[acur];
    int ce = min(cs + 16, ends0);
    bool fl0 = (ce == ends0);
    int csn = ce;
    int cen = min(csn + 16, fl0 ? ends1 : ends0);

    // prologue: chunk-0 jv -> DMA(0) -> chunk-0 regs + chunk-1 jv
    int jvN[4];
    {
        int jv0[4];
        #pragma unroll
        for (int it = 0; it < 4; ++it)
            jv0[it] = idx_j[min(cs + 4*it + g, E - 1)];
        asm volatile("" ::: "memory");
        #pragma unroll
        for (int it = 0; it < 4; ++it)
            load_lds16(hh + (size_t)jv0[it]*128 + ((ln ^ (2*it)) << 3),
                       &hsh[w][0][it*512]);
        asm volatile("" ::: "memory");
    }
    float4 fA, fB;
    {
        int e = min(cs + ln, E - 1);
        fA = *(const float4*)(f_ij + (size_t)e*20 + g*4);
        fB = *(const float4*)(f_ij + (size_t)e*20 + 16);
    }
    float rc[4];
    #pragma unroll
    for (int r2 = 0; r2 < 4; ++r2) rc[r2] = rcut[min(cs + 4*g + r2, E - 1)];
    #pragma unroll
    for (int it = 0; it < 4; ++it) jvN[it] = idx_j[min(csn + 4*it + g, E - 1)];
    asm volatile("" ::: "memory");

    float racc[8];
    #pragma unroll
    for (int q = 0; q < 8; ++q) racc[q] = 0.f;
    int p = 0;

    while (acur < aHi) {
        // ---- 1: DMA(k+1) into buf[p^1] (exactly 4 vmem between fences) ----
        asm volatile("" ::: "memory");
        #pragma unroll
        for (int it = 0; it < 4; ++it)
            load_lds16(hh + (size_t)jvN[it]*128 + ((ln ^ (2*it)) << 3),
                       &hsh[w][p^1][it*512]);
        // ---- 2: retire DMA(k) + ALL older loads; keep DMA(k+1) in flight ----
        asm volatile("s_waitcnt vmcnt(4)" ::: "memory");
        __builtin_amdgcn_sched_barrier(0);

        // ---- 3a: consume prefetched regs NOW ----
        half4_t blo = cvt4(fA.x, fA.y, fA.z, fA.w);
        half4_t bhi;
        if (g == 0) bhi = cvt4(fB.x, fB.y, fB.z, fB.w);
        else { half4_t zz = {}; bhi = zz; }
        half8_t bf = __builtin_shufflevector(blo, bhi, 0, 1, 2, 3, 4, 5, 6, 7);
        float rcm[4];
        #pragma unroll
        for (int r2 = 0; r2 < 4; ++r2)
            rcm[r2] = (cs + 4*g + r2 < ce) ? rc[r2] : 0.f;
        const bool flushF = (ce == ends0);
        const bool f1 = (cen == (flushF ? ends1 : ends0));
        const int cs2 = cen;
        const int endsel = flushF ? (f1 ? ends2 : ends1) : (f1 ? ends1 : ends0);
        const int ce2 = min(cs2 + 16, endsel);

        // ---- 3b: prefetch chunk k+1 regs / chunk k+2 jv / atom window ----
        int jv2[4];
        #pragma unroll
        for (int it = 0; it < 4; ++it)
            jv2[it] = idx_j[min(cs2 + 4*it + g, E - 1)];
        float4 fA1, fB1;
        {
            int e = min(csn + ln, E - 1);
            fA1 = *(const float4*)(f_ij + (size_t)e*20 + g*4);
            fB1 = *(const float4*)(f_ij + (size_t)e*20 + 16);
        }
        float rc1[4];
        #pragma unroll
        for (int r2 = 0; r2 < 4; ++r2) rc1[r2] = rcut[min(csn + 4*g + r2, E - 1)];
        const int aeL = atom_start[min(acur + 4, N)];
        asm volatile("" ::: "memory");

        // ---- 4: phase 1 (K=32, one MFMA per rf) + folded softplus ----
        f32x4 z[8];
        #pragma unroll
        for (int rf = 0; rf < 8; ++rf)
            z[rf] = __builtin_amdgcn_mfma_f32_16x16x32_f16(w1f[rf], bf, (f32x4)0.f, 0, 0, 0);
        half8_t a2[4];
        #pragma unroll
        for (int t = 0; t < 4; ++t) {
            float4 bbA = *(const float4*)&b1s[(2*t)*16 + g*4];
            float4 bbB = *(const float4*)&b1s[(2*t+1)*16 + g*4];
            float l0 = __log2f(1.f + exp2f(fmaf(z[2*t][0],   LOG2EF, bbA.x)));
            float l1 = __log2f(1.f + exp2f(fmaf(z[2*t][1],   LOG2EF, bbA.y)));
            float l2 = __log2f(1.f + exp2f(fmaf(z[2*t][2],   LOG2EF, bbA.z)));
            float l3 = __log2f(1.f + exp2f(fmaf(z[2*t][3],   LOG2EF, bbA.w)));
            float l4 = __log2f(1.f + exp2f(fmaf(z[2*t+1][0], LOG2EF, bbB.x)));
            float l5 = __log2f(1.f + exp2f(fmaf(z[2*t+1][1], LOG2EF, bbB.y)));
            float l6 = __log2f(1.f + exp2f(fmaf(z[2*t+1][2], LOG2EF, bbB.z)));
            float l7 = __log2f(1.f + exp2f(fmaf(z[2*t+1][3], LOG2EF, bbB.w)));
            a2[t] = pk8(l0, l1, l2, l3, l4, l5, l6, l7);
        }

        // ---- 5: phase 2 half 1 (nt 0..3), acc seeded with b2' ----
        f32x4 acc[4];
        #pragma unroll
        for (int q = 0; q < 4; ++q) { f32x4 t = {b2v[q], b2v[q], b2v[q], b2v[q]}; acc[q] = t; }
        __builtin_amdgcn_s_setprio(1);
        #pragma unroll
        for (int t = 0; t < 4; ++t)
            #pragma unroll
            for (int q = 0; q < 4; ++q) {
                half8_t bw = *(const half8_t*)&W2s[(((t*8 + q)*4 + g)*16 + ln)*8];
                acc[q] = __builtin_amdgcn_mfma_f32_16x16x32_f16(a2[t], bw, acc[q], 0, 0, 0);
            }
        __builtin_amdgcn_s_setprio(0);

        // ---- 6: epilogue half 1 ----
        #pragma unroll
        for (int q = 0; q < 4; ++q) {
            float s = 0.f;
            #pragma unroll
            for (int r2 = 0; r2 < 4; ++r2) {
                int segp = (2*q + lnh) ^ (2*g);
                float hv = (float)hsh[w][p][(4*g + r2)*128 + segp*8 + lnlo];
                s = fmaf(acc[q][r2] * rcm[r2], hv, s);
            }
            racc[q] += s;
        }

        // ---- 7: phase 2 half 2 (nt 4..7) + epilogue half 2 ----
        #pragma unroll
        for (int q = 0; q < 4; ++q) { f32x4 t = {b2v[4+q], b2v[4+q], b2v[4+q], b2v[4+q]}; acc[q] = t; }
        __builtin_amdgcn_s_setprio(1);
        #pragma unroll
        for (int t = 0; t < 4; ++t)
            #pragma unroll
            for (int q = 0; q < 4; ++q) {
                half8_t bw = *(const half8_t*)&W2s[(((t*8 + 4 + q)*4 + g)*16 + ln)*8];
                acc[q] = __builtin_amdgcn_mfma_f32_16x16x32_f16(a2[t], bw, acc[q], 0, 0, 0);
            }
        __builtin_amdgcn_s_setprio(0);
        #pragma unroll
        for (int q = 0; q < 4; ++q) {
            int nt = 4 + q;
            float s = 0.f;
            #pragma unroll
            for (int r2 = 0; r2 < 4; ++r2) {
                int segp = (2*nt + lnh) ^ (2*g);
                float hv = (float)hsh[w][p][(4*g + r2)*128 + segp*8 + lnlo];
                s = fmaf(acc[q][r2] * rcm[r2], hv, s);
            }
            racc[nt] += s;
        }

        // ---- 8: atom flush ----
        if (flushF) {
            #pragma unroll
            for (int q = 0; q < 8; ++q) {
                float r = racc[q];
                r += __shfl_xor(r, 16, 64);
                r += __shfl_xor(r, 32, 64);
                racc[q] = r;
            }
            if (g == 0) {
                #pragma unroll
                for (int q = 0; q < 8; ++q)
                    agg[(size_t)acur*128 + q*16 + ln] = racc[q];
            }
            #pragma unroll
            for (int q = 0; q < 8; ++q) racc[q] = 0.f;
            ++acur;
            ends0 = ends1; ends1 = ends2; ends2 = aeL;
        }

        // ---- 9: rotate pipeline state ----
        cs = csn; ce = cen; csn = cs2; cen = ce2;
        #pragma unroll
        for (int it = 0; it < 4; ++it) jvN[it] = jv2[it];
        fA = fA1; fB = fB1;
        #pragma unroll
        for (int r2 = 0; r2 < 4; ++r2) rc[r2] = rc1[r2];
        p ^= 1;
    }
}

extern "C" void kernel_launch(void* const* d_in, const int* in_sizes, int n_in,
                              void* d_out, int out_size, void* d_ws, size_t ws_size,
                              hipStream_t stream)
{
    const float* x      = (const float*)d_in[0];
    const float* f_ij   = (const float*)d_in[1];
    const float* rcut   = (const float*)d_in[2];
    const int*   idx_i  = (const int*)d_in[3];
    const int*   idx_j  = (const int*)d_in[4];
    const float* W_in2f = (const float*)d_in[5];
    const float* W_f1   = (const float*)d_in[6];
    const float* b_f1   = (const float*)d_in[7];
    const float* W_f2   = (const float*)d_in[8];
    const float* b_f2   = (const float*)d_in[9];
    const float* W_o1   = (const float*)d_in[10];
    const float* b_o1   = (const float*)d_in[11];
    const float* W_o2   = (const float*)d_in[12];
    const float* b_o2   = (const float*)d_in[13];

    const int N = in_sizes[0] / 128;
    const int E = in_sizes[2];

    half_t* h16  = (half_t*)d_ws;                       // [N,128] f16
    half_t* wt   = (half_t*)((char*)d_ws + (size_t)N * 128 * 4);
    half_t* Wt_in2f = wt;                 // 16384 halfs
    half_t* Wt_f1   = wt + 16384;         //  4096 (x32-padded [n][32])
    half_t* W2L     = wt + 16384 + 4096;  // 16384 (x32 stacked W_f2 * ln2)
    half_t* Wt_o1   = W2L + 16384;        // 16384
    half_t* Wt_o2   = Wt_o1 + 16384;      // 16384
    float*  b1sc    = (float*)(Wt_o2 + 16384);          // 128 floats
    float*  b2a     = b1sc + 128;                       // 128 floats
    int* atom_start = (int*)(b2a + 128);                // N+1 ints

    prep_weights<<<273, 256, 0, stream>>>(W_in2f, W_f1, W_f2, W_o1, W_o2,
                                          b_f1, b_f2,
                                          Wt_in2f, Wt_f1, W2L, Wt_o1, Wt_o2,
                                          b1sc, b2a);
    seg_starts<<<(E + 255) / 256, 256, 0, stream>>>(idx_i, atom_start, E, N);

    const int gn  = (N + 63) / 64;
    const int nbl = 512;                  // 4 waves/block, 2 blocks/CU
    const int W   = nbl * 4;

    // h = x @ W_in2f -> f16
    mfma_gemm_h<<<gn, 256, 0, stream>>>(x, Wt_in2f, h16, N);

    // wave-independent fused edge pipeline -> agg (writes every atom row once)
    edge_kernel<<<nbl, 256, 0, stream>>>(f_ij, rcut, idx_j,
                                         Wt_f1, b1sc, W2L, b2a,
                                         h16, (float*)d_out, atom_start, E, N, W);

    // out = ssp(agg @ W_o1 + b_o1) @ W_o2 + b_o2   (fused, in-place on d_out)
    mfma_gemm2<<<gn, 256, 0, stream>>>((const float*)d_out, Wt_o1, b_o1,
                                       Wt_o2, b_o2, (float*)d_out, N);
}

// Round 13
// 261.042 us; speedup vs baseline: 3.7915x; 1.0245x over previous
//
#include <hip/hip_runtime.h>
#include <math.h>

#define LN2F 0.6931471805599453f
#define LOG2EF 1.4426950408889634f

typedef _Float16 half_t;
typedef _Float16 half4_t __attribute__((ext_vector_type(4)));
typedef _Float16 half8_t __attribute__((ext_vector_type(8)));
typedef __fp16 fp16x2 __attribute__((ext_vector_type(2)));
typedef __fp16 fp16x4 __attribute__((ext_vector_type(4)));
typedef __fp16 fp16x8 __attribute__((ext_vector_type(8)));
typedef float f32x4 __attribute__((ext_vector_type(4)));

__device__ __forceinline__ float sspf(float z) {   // safe version (node MLP)
    return fmaxf(z, 0.f) + __logf(1.f + __expf(-fabsf(z))) - LN2F;
}
__device__ __forceinline__ half4_t cvt4(float x, float y, float z, float w) {
    half4_t r; r[0]=(half_t)x; r[1]=(half_t)y; r[2]=(half_t)z; r[3]=(half_t)w; return r;
}
// pack 8 floats to half8 via v_cvt_pkrtz_f16_f32 (4 instrs)
__device__ __forceinline__ half8_t pk8(float a, float b, float c, float d,
                                       float e, float f, float g, float h) {
    fp16x2 p0 = __builtin_amdgcn_cvt_pkrtz(a, b);
    fp16x2 p1 = __builtin_amdgcn_cvt_pkrtz(c, d);
    fp16x2 p2 = __builtin_amdgcn_cvt_pkrtz(e, f);
    fp16x2 p3 = __builtin_amdgcn_cvt_pkrtz(g, h);
    fp16x4 lo = __builtin_shufflevector(p0, p1, 0, 1, 2, 3);
    fp16x4 hi = __builtin_shufflevector(p2, p3, 0, 1, 2, 3);
    fp16x8 v  = __builtin_shufflevector(lo, hi, 0, 1, 2, 3, 4, 5, 6, 7);
    return __builtin_bit_cast(half8_t, v);
}

// async global->LDS DMA, 16 B per lane; dest = wave-uniform base + lane*16
__device__ __forceinline__ void load_lds16(const void* g, void* l) {
    __builtin_amdgcn_global_load_lds(
        (const __attribute__((address_space(1))) unsigned int*)g,
        (__attribute__((address_space(3))) unsigned int*)l, 16, 0, 0);
}

__device__ __forceinline__ int lbound(const int* __restrict__ a, int n, int key) {
    int lo = 0, hi = n;
    while (lo < hi) { int m = (lo + hi) >> 1; if (a[m] < key) lo = m + 1; else hi = m; }
    return lo;
}

// Weight prep.
//  Wt_in2f/Wt_o1/Wt_o2: dst[n*128+k] = W[k][n]  (f16)
//  Wt_f1: dst[n*32+k] = W_f1[k][n], k<20 else 0   (x32 A-frags, K-padded)
//  W2L (x32-stacked layout, pre-scaled by ln2; R13: out-col = ln*8 + nt):
//    flat i: j=i&7, ln=(i>>3)&15, g=(i>>7)&3, nt=(i>>9)&7, t=i>>12
//    k = 32t + (j<4 ? g*4+j : 16+g*4+(j-4))
//    W2L[i] = ln2 * W_f2[k*128 + ln*8 + nt]
//  b1sc = b_f1*log2e ; b2a = b_f2 - ln2*colsum(W_f2)
__global__ __launch_bounds__(256) void prep_weights(
    const float* __restrict__ W_in2f, const float* __restrict__ W_f1,
    const float* __restrict__ W_f2, const float* __restrict__ W_o1,
    const float* __restrict__ W_o2,
    const float* __restrict__ b_f1, const float* __restrict__ b_f2,
    half_t* __restrict__ Wt_in2f, half_t* __restrict__ Wt_f1,
    half_t* __restrict__ W2L, half_t* __restrict__ Wt_o1,
    half_t* __restrict__ Wt_o2, float* __restrict__ b1sc, float* __restrict__ b2a)
{
    int b = blockIdx.x;
    if (b < 64) {
        int i = b*256 + threadIdx.x;
        Wt_in2f[i] = (half_t)W_in2f[(i & 127)*128 + (i >> 7)];
    } else if (b < 80) {
        int i = (b-64)*256 + threadIdx.x;
        int n = i >> 5, k = i & 31;
        Wt_f1[i] = (k < 20) ? (half_t)W_f1[k*128 + n] : (half_t)0.f;
    } else if (b < 144) {
        int i = (b-80)*256 + threadIdx.x;     // 0..16383
        int j = i & 7, ln = (i >> 3) & 15, g = (i >> 7) & 3;
        int nt = (i >> 9) & 7, t = i >> 12;
        int k = 32*t + ((j < 4) ? (g*4 + j) : (16 + g*4 + (j - 4)));
        W2L[i] = (half_t)(LN2F * W_f2[k*128 + ln*8 + nt]);
    } else if (b < 208) {
        int i = (b-144)*256 + threadIdx.x;
        Wt_o1[i] = (half_t)W_o1[(i & 127)*128 + (i >> 7)];
    } else if (b < 272) {
        int i = (b-208)*256 + threadIdx.x;
        Wt_o2[i] = (half_t)W_o2[(i & 127)*128 + (i >> 7)];
    } else {
        int c = threadIdx.x;
        if (c < 128) {
            float s = 0.f;
            for (int k = 0; k < 128; ++k) s += W_f2[k*128 + c];
            b2a[c]  = b_f2[c] - LN2F * s;
            b1sc[c] = b_f1[c] * LOG2EF;
        }
    }
}

// atom_start[a] = first edge index with idx_i >= a; atom_start[N] = E
__global__ __launch_bounds__(256) void seg_starts(
    const int* __restrict__ idx_i, int* __restrict__ atom_start, int E, int N)
{
    int e = blockIdx.x * 256 + threadIdx.x;
    if (e >= E) return;
    int a = idx_i[e];
    int prev = (e == 0) ? -1 : idx_i[e - 1];
    for (int k = prev + 1; k <= a; ++k) atom_start[k] = e;
    if (e == E - 1)
        for (int k = a + 1; k <= N; ++k) atom_start[k] = E;
}

// h = x @ W_in2f -> f16
__global__ __launch_bounds__(256) void mfma_gemm_h(
    const float* __restrict__ A, const half_t* __restrict__ Bt,
    half_t* __restrict__ Ch, int nrows)
{
    const int tid = threadIdx.x;
    const int w = tid >> 6, l = tid & 63, g = l >> 4, ln = l & 15;
    const int r0 = blockIdx.x * 64;

    f32x4 acc[4][2];
    #pragma unroll
    for (int rf = 0; rf < 4; ++rf)
        #pragma unroll
        for (int cf = 0; cf < 2; ++cf) acc[rf][cf] = (f32x4)0.f;

    #pragma unroll
    for (int kk = 0; kk < 8; ++kk) {
        const int kb = kk * 16 + g * 4;
        half4_t a[4];
        #pragma unroll
        for (int rf = 0; rf < 4; ++rf) {
            int r = r0 + rf * 16 + ln;
            int rr = r < nrows ? r : nrows - 1;
            float4 av = *(const float4*)(A + (size_t)rr * 128 + kb);
            a[rf] = cvt4(av.x, av.y, av.z, av.w);
        }
        #pragma unroll
        for (int cf = 0; cf < 2; ++cf) {
            int n = w * 32 + cf * 16 + ln;
            half4_t b = *(const half4_t*)(Bt + (size_t)n * 128 + kb);
            #pragma unroll
            for (int rf = 0; rf < 4; ++rf)
                acc[rf][cf] = __builtin_amdgcn_mfma_f32_16x16x16f16(a[rf], b, acc[rf][cf], 0, 0, 0);
        }
    }
    #pragma unroll
    for (int cf = 0; cf < 2; ++cf) {
        int n = w * 32 + cf * 16 + ln;
        #pragma unroll
        for (int rf = 0; rf < 4; ++rf)
            #pragma unroll
            for (int reg = 0; reg < 4; ++reg) {
                int r = r0 + rf * 16 + g * 4 + reg;
                if (r < nrows) Ch[(size_t)r * 128 + n] = (half_t)acc[rf][cf][reg];
            }
    }
}

// fused out-MLP: out = ssp(agg@O1+b1)@O2+b2  (t staged in LDS f16)
__global__ __launch_bounds__(256) void mfma_gemm2(
    const float* __restrict__ A, const half_t* __restrict__ Bt1,
    const float* __restrict__ bias1, const half_t* __restrict__ Bt2,
    const float* __restrict__ bias2, float* __restrict__ out, int nrows)
{
    __shared__ half_t ts[64][136];
    const int tid = threadIdx.x;
    const int w = tid >> 6, l = tid & 63, g = l >> 4, ln = l & 15;
    const int r0 = blockIdx.x * 64;

    // layer 1
    f32x4 acc[4][2];
    #pragma unroll
    for (int rf = 0; rf < 4; ++rf)
        #pragma unroll
        for (int cf = 0; cf < 2; ++cf) acc[rf][cf] = (f32x4)0.f;
    #pragma unroll
    for (int kk = 0; kk < 8; ++kk) {
        const int kb = kk * 16 + g * 4;
        half4_t a[4];
        #pragma unroll
        for (int rf = 0; rf < 4; ++rf) {
            int r = r0 + rf * 16 + ln;
            int rr = r < nrows ? r : nrows - 1;
            float4 av = *(const float4*)(A + (size_t)rr * 128 + kb);
            a[rf] = cvt4(av.x, av.y, av.z, av.w);
        }
        #pragma unroll
        for (int cf = 0; cf < 2; ++cf) {
            int n = w * 32 + cf * 16 + ln;
            half4_t b = *(const half4_t*)(Bt1 + (size_t)n * 128 + kb);
            #pragma unroll
            for (int rf = 0; rf < 4; ++rf)
                acc[rf][cf] = __builtin_amdgcn_mfma_f32_16x16x16f16(a[rf], b, acc[rf][cf], 0, 0, 0);
        }
    }
    #pragma unroll
    for (int cf = 0; cf < 2; ++cf) {
        int n = w * 32 + cf * 16 + ln;
        float bv = bias1[n];
        #pragma unroll
        for (int rf = 0; rf < 4; ++rf)
            #pragma unroll
            for (int reg = 0; reg < 4; ++reg)
                ts[rf*16 + g*4 + reg][n] = (half_t)sspf(acc[rf][cf][reg] + bv);
    }
    __syncthreads();

    // layer 2
    f32x4 acc2[4][2];
    #pragma unroll
    for (int rf = 0; rf < 4; ++rf)
        #pragma unroll
        for (int cf = 0; cf < 2; ++cf) acc2[rf][cf] = (f32x4)0.f;
    #pragma unroll
    for (int kk = 0; kk < 8; ++kk) {
        const int kb = kk * 16 + g * 4;
        half4_t a[4];
        #pragma unroll
        for (int rf = 0; rf < 4; ++rf)
            a[rf] = *(const half4_t*)&ts[rf*16 + ln][kb];
        #pragma unroll
        for (int cf = 0; cf < 2; ++cf) {
            int n = w * 32 + cf * 16 + ln;
            half4_t b = *(const half4_t*)(Bt2 + (size_t)n * 128 + kb);
            #pragma unroll
            for (int rf = 0; rf < 4; ++rf)
                acc2[rf][cf] = __builtin_amdgcn_mfma_f32_16x16x16f16(a[rf], b, acc2[rf][cf], 0, 0, 0);
        }
    }
    #pragma unroll
    for (int cf = 0; cf < 2; ++cf) {
        int n = w * 32 + cf * 16 + ln;
        float bv = bias2[n];
        #pragma unroll
        for (int rf = 0; rf < 4; ++rf)
            #pragma unroll
            for (int reg = 0; reg < 4; ++reg) {
                int r = r0 + rf * 16 + g * 4 + reg;
                if (r < nrows) out[(size_t)r * 128 + n] = acc2[rf][cf][reg] + bv;
            }
    }
}

// Wave-independent edge pipeline, double-buffered h-DMA, counted vmcnt.
// R13: out-col = ln*8+nt remap -> epilogue h reads = 4x ds_read_b128,
// coalesced float4 flush stores, merged 32-MFMA phase 2, persistent b2 seed.
__global__ __launch_bounds__(256, 2) void edge_kernel(
    const float* __restrict__ f_ij, const float* __restrict__ rcut,
    const int* __restrict__ idx_j,
    const half_t* __restrict__ Wt_f1, const float* __restrict__ b1sc,
    const half_t* __restrict__ W2L, const float* __restrict__ b2a,
    const half_t* __restrict__ hh, float* __restrict__ agg,
    const int* __restrict__ atom_start, int E, int N, int W)
{
    __shared__ __align__(16) half_t W2s[16384];        // 32768 B
    __shared__ __align__(16) half_t hsh[4][2][2048];   // 32768 B (dbuf, 4KB/wave)
    __shared__ float b1s[128];                         //   512 B
    // 66048 B -> 2 blocks/CU

    const int tid = threadIdx.x;
    const int w = tid >> 6, l = tid & 63, g = l >> 4, ln = l & 15;

    for (int i = tid; i < 2048; i += 256)
        ((float4*)W2s)[i] = ((const float4*)W2L)[i];
    if (tid < 128) b1s[tid] = b1sc[tid];
    __syncthreads();

    // per-wave atom range (edge-balanced)
    const int kg = blockIdx.x * 4 + w;
    const int aLo = lbound(atom_start, N + 1, (int)((size_t)kg * E / W));
    const int aHi = (kg == W - 1) ? N
                  : lbound(atom_start, N + 1, (int)((size_t)(kg + 1) * E / W));
    if (aLo >= aHi) return;

    // W1 A-frags in VGPRs (x32 stacked-K)
    half8_t w1f[8];
    #pragma unroll
    for (int rf = 0; rf < 8; ++rf) {
        half4_t lo = *(const half4_t*)(Wt_f1 + (size_t)(rf*16 + ln)*32 + g*4);
        half4_t hi = *(const half4_t*)(Wt_f1 + (size_t)(rf*16 + ln)*32 + 16 + g*4);
        w1f[rf] = __builtin_shufflevector(lo, hi, 0, 1, 2, 3, 4, 5, 6, 7);
    }

    // persistent b2' accumulator seeds (lane cols = ln*8 .. ln*8+7)
    f32x4 b2acc[8];
    {
        float4 blo4 = *(const float4*)(b2a + ln*8);
        float4 bhi4 = *(const float4*)(b2a + ln*8 + 4);
        float bv[8] = {blo4.x, blo4.y, blo4.z, blo4.w, bhi4.x, bhi4.y, bhi4.z, bhi4.w};
        #pragma unroll
        for (int q = 0; q < 8; ++q) {
            f32x4 t = {bv[q], bv[q], bv[q], bv[q]};
            b2acc[q] = t;
        }
    }

    // atom window + chunk bounds
    int acur = aLo;
    int ends0 = atom_start[acur + 1];
    int ends1 = atom_start[min(acur + 2, N)];
    int ends2 = atom_start[min(acur + 3, N)];
    int cs = atom_start[acur];
    int ce = min(cs + 16, ends0);
    bool fl0 = (ce == ends0);
    int csn = ce;
    int cen = min(csn + 16, fl0 ? ends1 : ends0);

    // prologue: chunk-0 jv -> DMA(0) -> chunk-0 regs + chunk-1 jv
    int jvN[4];
    {
        int jv0[4];
        #pragma unroll
        for (int it = 0; it < 4; ++it)
            jv0[it] = idx_j[min(cs + 4*it + g, E - 1)];
        asm volatile("" ::: "memory");
        #pragma unroll
        for (int it = 0; it < 4; ++it)
            load_lds16(hh + (size_t)jv0[it]*128 + ((ln ^ it) << 3),
                       &hsh[w][0][it*512]);
        asm volatile("" ::: "memory");
    }
    float4 fA, fB;
    {
        int e = min(cs + ln, E - 1);
        fA = *(const float4*)(f_ij + (size_t)e*20 + g*4);
        fB = *(const float4*)(f_ij + (size_t)e*20 + 16);
    }
    float rc[4];
    #pragma unroll
    for (int r2 = 0; r2 < 4; ++r2) rc[r2] = rcut[min(cs + 4*g + r2, E - 1)];
    #pragma unroll
    for (int it = 0; it < 4; ++it) jvN[it] = idx_j[min(csn + 4*it + g, E - 1)];
    asm volatile("" ::: "memory");

    float racc[8];
    #pragma unroll
    for (int q = 0; q < 8; ++q) racc[q] = 0.f;
    int p = 0;

    while (acur < aHi) {
        // ---- 1: DMA(k+1) into buf[p^1] (exactly 4 vmem between fences) ----
        asm volatile("" ::: "memory");
        #pragma unroll
        for (int it = 0; it < 4; ++it)
            load_lds16(hh + (size_t)jvN[it]*128 + ((ln ^ it) << 3),
                       &hsh[w][p^1][it*512]);
        // ---- 2: retire DMA(k) + ALL older loads; keep DMA(k+1) in flight ----
        asm volatile("s_waitcnt vmcnt(4)" ::: "memory");
        __builtin_amdgcn_sched_barrier(0);

        // ---- 3a: consume prefetched regs NOW ----
        half4_t blo = cvt4(fA.x, fA.y, fA.z, fA.w);
        half4_t bhi;
        if (g == 0) bhi = cvt4(fB.x, fB.y, fB.z, fB.w);
        else { half4_t zz = {}; bhi = zz; }
        half8_t bf = __builtin_shufflevector(blo, bhi, 0, 1, 2, 3, 4, 5, 6, 7);
        float rcm[4];
        #pragma unroll
        for (int r2 = 0; r2 < 4; ++r2)
            rcm[r2] = (cs + 4*g + r2 < ce) ? rc[r2] : 0.f;
        const bool flushF = (ce == ends0);
        const bool f1 = (cen == (flushF ? ends1 : ends0));
        const int cs2 = cen;
        const int endsel = flushF ? (f1 ? ends2 : ends1) : (f1 ? ends1 : ends0);
        const int ce2 = min(cs2 + 16, endsel);

        // ---- 3b: prefetch chunk k+1 regs / chunk k+2 jv / atom window ----
        int jv2[4];
        #pragma unroll
        for (int it = 0; it < 4; ++it)
            jv2[it] = idx_j[min(cs2 + 4*it + g, E - 1)];
        float4 fA1, fB1;
        {
            int e = min(csn + ln, E - 1);
            fA1 = *(const float4*)(f_ij + (size_t)e*20 + g*4);
            fB1 = *(const float4*)(f_ij + (size_t)e*20 + 16);
        }
        float rc1[4];
        #pragma unroll
        for (int r2 = 0; r2 < 4; ++r2) rc1[r2] = rcut[min(csn + 4*g + r2, E - 1)];
        const int aeL = atom_start[min(acur + 4, N)];
        asm volatile("" ::: "memory");

        // ---- 4: phase 1 (K=32) + folded softplus: a2 = log2(1 + 2^u) ----
        f32x4 z[8];
        #pragma unroll
        for (int rf = 0; rf < 8; ++rf)
            z[rf] = __builtin_amdgcn_mfma_f32_16x16x32_f16(w1f[rf], bf, (f32x4)0.f, 0, 0, 0);
        half8_t a2[4];
        #pragma unroll
        for (int t = 0; t < 4; ++t) {
            float4 bbA = *(const float4*)&b1s[(2*t)*16 + g*4];
            float4 bbB = *(const float4*)&b1s[(2*t+1)*16 + g*4];
            float l0 = __log2f(1.f + exp2f(fmaf(z[2*t][0],   LOG2EF, bbA.x)));
            float l1 = __log2f(1.f + exp2f(fmaf(z[2*t][1],   LOG2EF, bbA.y)));
            float l2 = __log2f(1.f + exp2f(fmaf(z[2*t][2],   LOG2EF, bbA.z)));
            float l3 = __log2f(1.f + exp2f(fmaf(z[2*t][3],   LOG2EF, bbA.w)));
            float l4 = __log2f(1.f + exp2f(fmaf(z[2*t+1][0], LOG2EF, bbB.x)));
            float l5 = __log2f(1.f + exp2f(fmaf(z[2*t+1][1], LOG2EF, bbB.y)));
            float l6 = __log2f(1.f + exp2f(fmaf(z[2*t+1][2], LOG2EF, bbB.z)));
            float l7 = __log2f(1.f + exp2f(fmaf(z[2*t+1][3], LOG2EF, bbB.w)));
            a2[t] = pk8(l0, l1, l2, l3, l4, l5, l6, l7);
        }

        // ---- 5: phase 2 merged (32 MFMA), acc seeded from persistent b2acc ----
        f32x4 acc[8];
        #pragma unroll
        for (int q = 0; q < 8; ++q) acc[q] = b2acc[q];
        __builtin_amdgcn_s_setprio(1);
        #pragma unroll
        for (int t = 0; t < 4; ++t)
            #pragma unroll
            for (int q = 0; q < 8; ++q) {
                half8_t bw = *(const half8_t*)&W2s[(((t*8 + q)*4 + g)*16 + ln)*8];
                acc[q] = __builtin_amdgcn_mfma_f32_16x16x32_f16(a2[t], bw, acc[q], 0, 0, 0);
            }
        __builtin_amdgcn_s_setprio(0);

        // ---- 6: epilogue — 4x ds_read_b128 (cols ln*8..ln*8+7 per edge-row) ----
        #pragma unroll
        for (int r2 = 0; r2 < 4; ++r2) {
            half8_t hv8 = *(const half8_t*)&hsh[w][p][(4*g + r2)*128 + ((ln ^ g) << 3)];
            float rr = rcm[r2];
            #pragma unroll
            for (int q = 0; q < 8; ++q)
                racc[q] = fmaf(acc[q][r2] * rr, (float)hv8[q], racc[q]);
        }

        // ---- 7: atom flush (coalesced float4 stores) ----
        if (flushF) {
            #pragma unroll
            for (int q = 0; q < 8; ++q) {
                float r = racc[q];
                r += __shfl_xor(r, 16, 64);
                r += __shfl_xor(r, 32, 64);
                racc[q] = r;
            }
            if (g == 0) {
                float4 v0 = {racc[0], racc[1], racc[2], racc[3]};
                float4 v1 = {racc[4], racc[5], racc[6], racc[7]};
                *(float4*)(agg + (size_t)acur*128 + ln*8)     = v0;
                *(float4*)(agg + (size_t)acur*128 + ln*8 + 4) = v1;
            }
            #pragma unroll
            for (int q = 0; q < 8; ++q) racc[q] = 0.f;
            ++acur;
            ends0 = ends1; ends1 = ends2; ends2 = aeL;
        }

        // ---- 8: rotate pipeline state ----
        cs = csn; ce = cen; csn = cs2; cen = ce2;
        #pragma unroll
        for (int it = 0; it < 4; ++it) jvN[it] = jv2[it];
        fA = fA1; fB = fB1;
        #pragma unroll
        for (int r2 = 0; r2 < 4; ++r2) rc[r2] = rc1[r2];
        p ^= 1;
    }
}

extern "C" void kernel_launch(void* const* d_in, const int* in_sizes, int n_in,
                              void* d_out, int out_size, void* d_ws, size_t ws_size,
                              hipStream_t stream)
{
    const float* x      = (const float*)d_in[0];
    const float* f_ij   = (const float*)d_in[1];
    const float* rcut   = (const float*)d_in[2];
    const int*   idx_i  = (const int*)d_in[3];
    const int*   idx_j  = (const int*)d_in[4];
    const float* W_in2f = (const float*)d_in[5];
    const float* W_f1   = (const float*)d_in[6];
    const float* b_f1   = (const float*)d_in[7];
    const float* W_f2   = (const float*)d_in[8];
    const float* b_f2   = (const float*)d_in[9];
    const float* W_o1   = (const float*)d_in[10];
    const float* b_o1   = (const float*)d_in[11];
    const float* W_o2   = (const float*)d_in[12];
    const float* b_o2   = (const float*)d_in[13];

    const int N = in_sizes[0] / 128;
    const int E = in_sizes[2];

    half_t* h16  = (half_t*)d_ws;                       // [N,128] f16
    half_t* wt   = (half_t*)((char*)d_ws + (size_t)N * 128 * 4);
    half_t* Wt_in2f = wt;                 // 16384 halfs
    half_t* Wt_f1   = wt + 16384;         //  4096 (x32-padded [n][32])
    half_t* W2L     = wt + 16384 + 4096;  // 16384 (x32 stacked W_f2 * ln2)
    half_t* Wt_o1   = W2L + 16384;        // 16384
    half_t* Wt_o2   = Wt_o1 + 16384;      // 16384
    float*  b1sc    = (float*)(Wt_o2 + 16384);          // 128 floats
    float*  b2a     = b1sc + 128;                       // 128 floats
    int* atom_start = (int*)(b2a + 128);                // N+1 ints

    prep_weights<<<273, 256, 0, stream>>>(W_in2f, W_f1, W_f2, W_o1, W_o2,
                                          b_f1, b_f2,
                                          Wt_in2f, Wt_f1, W2L, Wt_o1, Wt_o2,
                                          b1sc, b2a);
    seg_starts<<<(E + 255) / 256, 256, 0, stream>>>(idx_i, atom_start, E, N);

    const int gn  = (N + 63) / 64;
    const int nbl = 512;                  // 4 waves/block, 2 blocks/CU
    const int W   = nbl * 4;

    // h = x @ W_in2f -> f16
    mfma_gemm_h<<<gn, 256, 0, stream>>>(x, Wt_in2f, h16, N);

    // wave-independent fused edge pipeline -> agg (writes every atom row once)
    edge_kernel<<<nbl, 256, 0, stream>>>(f_ij, rcut, idx_j,
                                         Wt_f1, b1sc, W2L, b2a,
                                         h16, (float*)d_out, atom_start, E, N, W);

    // out = ssp(agg @ W_o1 + b_o1) @ W_o2 + b_o2   (fused, in-place on d_out)
    mfma_gemm2<<<gn, 256, 0, stream>>>((const float*)d_out, Wt_o1, b_o1,
                                       Wt_o2, b_o2, (float*)d_out, N);
}